// Round 2
// baseline (716.616 us; speedup 1.0000x reference)
//
#include <hip/hip_runtime.h>

typedef unsigned int  u32;
typedef unsigned char u8;

#define B_TOT 512
#define L_SEQ 256
#define D_IN  64
#define HIDN  256
#define TOPK  128

// ---------- helpers ----------
// monotonic float->uint key (descending float order == descending uint order)
__device__ __forceinline__ u32 sortKey(float f){
  u32 b = __float_as_uint(f);
  return (b & 0x80000000u) ? ~b : (b | 0x80000000u);
}
__device__ __forceinline__ float unKey(u32 u){
  u32 b = (u & 0x80000000u) ? (u & 0x7fffffffu) : ~u;
  return __uint_as_float(b);
}
// block(256)-wide sum of ints; all threads get the total
__device__ __forceinline__ int blockCount(int c, int* red, int tid){
  #pragma unroll
  for (int off=32; off>0; off>>=1) c += __shfl_down(c, off);
  __syncthreads();                 // protect red[] from previous round
  if ((tid&63)==0) red[tid>>6] = c;
  __syncthreads();
  return red[0]+red[1]+red[2]+red[3];
}

// ---------- K0: M = Wq Wk^T (64x64), u = Wq bk, v = Wk bq, c = bq.bk ----------
// grid 64 (one block per M row), block 256
__global__ __launch_bounds__(256) void k_prep(
    const float* __restrict__ Wq, const float* __restrict__ bq,
    const float* __restrict__ Wk, const float* __restrict__ bk,
    float* __restrict__ M, float* __restrict__ uvc)
{
  __shared__ float wq[HIDN];
  __shared__ float part[256];
  int a = blockIdx.x, tid = threadIdx.x;
  wq[tid] = Wq[a*HIDN + tid];
  __syncthreads();
  int bcol = tid & 63, q = tid >> 6;     // 64 cols x 4 h-quarters
  float s = 0.f;
  for (int h = q*64; h < q*64 + 64; ++h)
    s = fmaf(wq[h], Wk[bcol*HIDN + h], s);
  part[tid] = s;
  __syncthreads();
  if (tid < 64)
    M[a*64 + tid] = part[tid] + part[64+tid] + part[128+tid] + part[192+tid];
  if (tid == 0){
    float su = 0.f;
    for (int h=0; h<HIDN; ++h) su = fmaf(wq[h], bk[h], su);
    uvc[a] = su;
  }
  if (tid == 1){
    float sv = 0.f;
    for (int h=0; h<HIDN; ++h) sv = fmaf(Wk[a*HIDN + h], bq[h], sv);
    uvc[64 + a] = sv;
  }
  if (a == 0 && tid == 2){
    float c = 0.f;
    for (int h=0; h<HIDN; ++h) c = fmaf(bq[h], bk[h], c);
    uvc[128] = c;
  }
}

// ---------- K1: y = x M, s_i = x.u + c, t_j = x.v, pad mask ----------
// grid dim3(4, B_TOT): 64 rows per block; block 256 = 64 rows x 4 col-groups
__global__ __launch_bounds__(256) void k_y(
    const float* __restrict__ x, const float* __restrict__ M,
    const float* __restrict__ uvc,
    float* __restrict__ y, float* __restrict__ st, u8* __restrict__ padm)
{
  __shared__ float sx[64][68];
  __shared__ float Ms[64][68];
  int tid = threadIdx.x;
  int b = blockIdx.y, r0 = blockIdx.x * 64;

  for (int q = tid; q < 64*16; q += 256){
    int r = q >> 4, a4 = (q & 15) * 4;
    *(float4*)&sx[r][a4] = *(const float4*)(x + ((size_t)b*L_SEQ + r0 + r)*D_IN + a4);
  }
  for (int q = tid; q < 64*16; q += 256){
    int a = q >> 4, b4 = (q & 15) * 4;
    *(float4*)&Ms[a][b4] = *(const float4*)(M + a*64 + b4);
  }
  __syncthreads();

  int r = tid >> 2, g = tid & 3;
  float acc[16];
  #pragma unroll
  for (int i=0;i<16;++i) acc[i]=0.f;
  for (int a=0; a<64; ++a){
    float xa = sx[r][a];
    #pragma unroll
    for (int j=0;j<4;++j){
      float4 m4 = *(const float4*)&Ms[a][g*16 + j*4];
      acc[j*4+0] = fmaf(xa, m4.x, acc[j*4+0]);
      acc[j*4+1] = fmaf(xa, m4.y, acc[j*4+1]);
      acc[j*4+2] = fmaf(xa, m4.z, acc[j*4+2]);
      acc[j*4+3] = fmaf(xa, m4.w, acc[j*4+3]);
    }
  }
  float* yp = y + ((size_t)b*L_SEQ + r0 + r)*D_IN + g*16;
  #pragma unroll
  for (int j=0;j<4;++j)
    *(float4*)(yp + j*4) = make_float4(acc[j*4],acc[j*4+1],acc[j*4+2],acc[j*4+3]);

  if (g == 0){
    float su = uvc[128], tv = 0.f, pa = 0.f;
    for (int a=0; a<64; ++a){
      float xa = sx[r][a];
      su = fmaf(xa, uvc[a], su);
      tv = fmaf(xa, uvc[64+a], tv);
      pa += fabsf(xa);
    }
    st[(size_t)b*L_SEQ + r0 + r]            = su;  // s_i + c
    st[(size_t)(B_TOT + b)*L_SEQ + r0 + r]  = tv;  // t_j
    padm[(size_t)b*L_SEQ + r0 + r] = (pa != 0.f) ? 1 : 0;
  }
}

// ---------- K2: scores16 = y.x^T + s_i + t_j, /16, fused exact per-tile top-128 ----------
// grid dim3(4, B_TOT): tile = 64 rows x 256 cols; block 256, 4x16 accs/thread
__global__ __launch_bounds__(256) void k_score(
    const float* __restrict__ y, const float* __restrict__ x,
    const float* __restrict__ st, const u8* __restrict__ padm,
    float* __restrict__ cand_v, int* __restrict__ cand_i)
{
  __shared__ float Ys[16][68];
  __shared__ float Xs[16][257];
  __shared__ int red[4];
  __shared__ int cm, eqc;
  __shared__ int eqi[256];
  int tid = threadIdx.x;
  int rb = blockIdx.x, b = blockIdx.y;
  int tx = tid & 15, ty = tid >> 4;

  float av[64];
  #pragma unroll
  for (int i=0;i<64;++i) av[i]=0.f;

  for (int k0=0; k0<D_IN; k0+=16){
    #pragma unroll
    for (int r2=0;r2<4;++r2){
      int e = tid + 256*r2; int row = e>>4, kk = e&15;
      Ys[kk][row] = y[((size_t)b*L_SEQ + rb*64 + row)*D_IN + k0 + kk];
    }
    #pragma unroll
    for (int r2=0;r2<16;++r2){
      int e = tid + 256*r2; int col = e>>4, kk = e&15;
      Xs[kk][col] = x[((size_t)b*L_SEQ + col)*D_IN + k0 + kk];
    }
    __syncthreads();
    #pragma unroll
    for (int kk=0;kk<16;++kk){
      float4 a4 = *(const float4*)&Ys[kk][ty*4];
      float ar[4]={a4.x,a4.y,a4.z,a4.w};
      #pragma unroll
      for (int dj=0;dj<16;++dj){
        float bv = Xs[kk][tx + 16*dj];
        #pragma unroll
        for (int di=0;di<4;++di)
          av[di*16+dj] = fmaf(ar[di], bv, av[di*16+dj]);
      }
    }
    __syncthreads();
  }

  // add rank-1 terms, scale, mask, convert to sortable key (bits held in av)
  float srow[4]; bool pr[4];
  #pragma unroll
  for (int di=0;di<4;++di){
    int l = rb*64 + ty*4 + di;
    srow[di] = st[(size_t)b*L_SEQ + l];
    pr[di]   = padm[(size_t)b*L_SEQ + l] != 0;
  }
  float tcol[16]; bool pc[16];
  #pragma unroll
  for (int dj=0;dj<16;++dj){
    int j = tx + 16*dj;
    tcol[dj] = st[(size_t)(B_TOT + b)*L_SEQ + j];
    pc[dj]   = padm[(size_t)b*L_SEQ + j] != 0;
  }
  const float NINF = __uint_as_float(0xff800000u);
  #pragma unroll
  for (int di=0;di<4;++di)
    #pragma unroll
    for (int dj=0;dj<16;++dj){
      float v = (pr[di]&&pc[dj]) ? (av[di*16+dj] + srow[di] + tcol[dj])*0.0625f : NINF;
      av[di*16+dj] = __uint_as_float(sortKey(v));
    }

  // binary search for the 128th-largest key in this tile (16384 values)
  u32 T = 0;
  for (int bit=31; bit>=0; --bit){
    u32 c2 = T | (1u<<bit);
    int c = 0;
    #pragma unroll
    for (int i=0;i<64;++i) c += (__float_as_uint(av[i]) >= c2) ? 1 : 0;
    if (blockCount(c,red,tid) >= TOPK) T = c2;
  }
  int cg = 0;
  #pragma unroll
  for (int i=0;i<64;++i) cg += (__float_as_uint(av[i]) > T) ? 1 : 0;
  int m = blockCount(cg,red,tid);
  if (tid==0){ cm=0; eqc=0; }
  __syncthreads();

  size_t base = ((size_t)b*4 + rb)*TOPK;
  #pragma unroll
  for (int i=0;i<64;++i){
    u32 u = __float_as_uint(av[i]);
    if (u >= T){
      int di = i>>4, dj = i&15;
      int flat = (rb*64 + ty*4 + di)*L_SEQ + (tx + 16*dj);
      if (u > T){
        int p = atomicAdd(&cm,1);
        cand_v[base+p] = unKey(u);
        cand_i[base+p] = flat;
      } else {
        int q = atomicAdd(&eqc,1);
        if (q < 256) eqi[q] = flat;
      }
    }
  }
  __syncthreads();
  if (tid==0){
    int need = TOPK - m;
    int n = eqc < 256 ? eqc : 256;
    float tv = unKey(T);
    for (int s=0; s<need; ++s){
      int src = 0;
      if (s < n){                       // lowest-index-first among ties
        int bi=s;
        for (int j=s+1;j<n;++j) if (eqi[j] < eqi[bi]) bi=j;
        int t2=eqi[s]; eqi[s]=eqi[bi]; eqi[bi]=t2;
        src = eqi[s];
      }
      cand_v[base+m+s] = tv;
      cand_i[base+m+s] = src;
    }
  }
}

// ---------- K3: merge 4x128 candidates -> exact global top-128 + softmax ----------
__global__ __launch_bounds__(256) void k_merge(
    const float* __restrict__ cand_v, const int* __restrict__ cand_i,
    int* __restrict__ selidx, float* __restrict__ selw)
{
  __shared__ int red[4]; __shared__ int cm, eqc; __shared__ int eqi[256];
  __shared__ float sv[TOPK]; __shared__ int si[TOPK];
  int b = blockIdx.x, tid = threadIdx.x;
  u32 u[2]; int id[2];
  #pragma unroll
  for (int j=0;j<2;++j){
    int e = tid + 256*j;
    u[j]  = sortKey(cand_v[(size_t)b*512 + e]);
    id[j] = cand_i[(size_t)b*512 + e];
  }
  u32 T=0;
  for (int bit=31;bit>=0;--bit){
    u32 c2 = T|(1u<<bit);
    int c = ((u[0]>=c2)?1:0) + ((u[1]>=c2)?1:0);
    if (blockCount(c,red,tid) >= TOPK) T=c2;
  }
  int m = blockCount(((u[0]>T)?1:0)+((u[1]>T)?1:0), red, tid);
  if (tid==0){cm=0;eqc=0;}
  __syncthreads();
  #pragma unroll
  for (int j=0;j<2;++j){
    if (u[j] > T){ int p=atomicAdd(&cm,1); sv[p]=unKey(u[j]); si[p]=id[j]; }
    else if (u[j]==T){ int q=atomicAdd(&eqc,1); if(q<256) eqi[q]=id[j]; }
  }
  __syncthreads();
  if (tid==0){
    int need = TOPK - m;
    int n = eqc<256?eqc:256;
    float tv = unKey(T);
    for (int s=0;s<need;++s){
      int src=0;
      if (s<n){ int bi=s; for(int j=s+1;j<n;++j) if (eqi[j]<eqi[bi]) bi=j;
                int t2=eqi[s];eqi[s]=eqi[bi];eqi[bi]=t2; src=eqi[s]; }
      sv[m+s]=tv; si[m+s]=src;
    }
    float mx=-3.4e38f;
    for (int k=0;k<TOPK;++k) mx = fmaxf(mx, sv[k]);
    float ssum=0.f;
    for (int k=0;k<TOPK;++k){ float e=expf(sv[k]-mx); sv[k]=e; ssum+=e; }
    float inv=1.f/ssum;
    for (int k=0;k<TOPK;++k){
      selw[(size_t)b*TOPK + k]   = sv[k]*inv;
      selidx[(size_t)b*TOPK + k] = si[k];
    }
  }
}

// ---------- K4: gather + MLP1 + weighted pooling (layer2 fused) + rho ----------
// grid B_TOT (batch), block 256 (hidden unit h)
__global__ __launch_bounds__(256) void k_mlp(
    const float* __restrict__ x, const int* __restrict__ selidx, const float* __restrict__ selw,
    const float* __restrict__ phi_w1, const float* __restrict__ phi_b1,
    const float* __restrict__ phi_w2, const float* __restrict__ phi_b2,
    const float* __restrict__ xi_w1,  const float* __restrict__ xi_b1,
    const float* __restrict__ xi_w2,  const float* __restrict__ xi_b2,
    const float* __restrict__ rho_w1, const float* __restrict__ rho_b1,
    const float* __restrict__ rho_w2, const float* __restrict__ rho_b2,
    float* __restrict__ out)
{
  __shared__ float sxc[64][128];          // xcat tile (k-tile of 64)
  __shared__ int   sidx[TOPK];
  __shared__ float swp[TOPK], swd[TOPK];  // pair-weight (0 if diag), diag-weight
  __shared__ float gpL[256], gsL[256];
  __shared__ float pooled[256], t1[256];
  __shared__ float wsums[2];
  int b = blockIdx.x, h = threadIdx.x;

  if (h < TOPK){
    int fl = selidx[(size_t)b*TOPK + h];
    sidx[h] = fl;
    float w = selw[(size_t)b*TOPK + h];
    bool dg = ((fl>>8) == (fl&255));
    swp[h] = dg ? 0.f : w;
    swd[h] = dg ? w   : 0.f;
  }
  __syncthreads();
  if (h==0){
    float a=0.f,c=0.f;
    for (int k=0;k<TOPK;++k){ a+=swp[k]; c+=swd[k]; }
    wsums[0]=a; wsums[1]=c;
  }

  float gp=0.f, gs=0.f;
  float bxi = xi_b1[h];
  float bph = phi_b1[h];

  for (int tile=0; tile<2; ++tile){
    __syncthreads();
    for (int i=0;i<32;++i){
      int e = h + 256*i; int k = e>>7, d = e&127;
      int fl = sidx[tile*64+k];
      int rc = (d<64) ? (fl>>8) : (fl&255);
      sxc[k][d] = x[((size_t)b*L_SEQ + rc)*D_IN + (d&63)];
    }
    __syncthreads();
    for (int kb=0; kb<64; kb+=8){
      float acc[8];
      #pragma unroll
      for (int j=0;j<8;++j) acc[j]=bxi;
      #pragma unroll 4
      for (int d0=0; d0<128; d0+=4){
        float w0 = xi_w1[(d0+0)*HIDN + h];
        float w1 = xi_w1[(d0+1)*HIDN + h];
        float w2 = xi_w1[(d0+2)*HIDN + h];
        float w3 = xi_w1[(d0+3)*HIDN + h];
        #pragma unroll
        for (int j=0;j<8;++j){
          float4 xv = *(const float4*)&sxc[kb+j][d0];
          acc[j] = fmaf(xv.x,w0,fmaf(xv.y,w1,fmaf(xv.z,w2,fmaf(xv.w,w3,acc[j]))));
        }
      }
      #pragma unroll
      for (int j=0;j<8;++j)
        gp += swp[tile*64+kb+j]*fmaxf(acc[j],0.f);
    }
    // diag rows (phi MLP on x_i = first 64 dims)
    for (int k=0;k<64;++k){
      float wd = swd[tile*64+k];
      if (wd != 0.f){
        float a = bph;
        #pragma unroll 4
        for (int d0=0; d0<64; d0+=4){
          float w0 = phi_w1[(d0+0)*HIDN + h];
          float w1 = phi_w1[(d0+1)*HIDN + h];
          float w2 = phi_w1[(d0+2)*HIDN + h];
          float w3 = phi_w1[(d0+3)*HIDN + h];
          float4 xv = *(const float4*)&sxc[k][d0];
          a = fmaf(xv.x,w0,fmaf(xv.y,w1,fmaf(xv.z,w2,fmaf(xv.w,w3,a))));
        }
        gs += wd*fmaxf(a,0.f);
      }
    }
  }
  gpL[h]=gp; gsL[h]=gs;
  __syncthreads();

  // pooled = gp @ xi_w2 + gs @ phi_w2 + wsp*xi_b2 + wss*phi_b2
  {
    float wsp=wsums[0], wss=wsums[1];
    float po = wsp*xi_b2[h] + wss*phi_b2[h];
    for (int d=0; d<256; ++d){
      po = fmaf(gpL[d], xi_w2[d*HIDN + h], po);
      po = fmaf(gsL[d], phi_w2[d*HIDN + h], po);
    }
    pooled[h]=po;
  }
  __syncthreads();
  {
    float a = rho_b1[h];
    for (int d=0; d<256; ++d) a = fmaf(pooled[d], rho_w1[d*HIDN + h], a);
    t1[h] = fmaxf(a,0.f);
  }
  __syncthreads();
  if (h < 128){
    float o = rho_b2[h];
    for (int d=0; d<256; ++d) o = fmaf(t1[d], rho_w2[d*128 + h], o);
    out[(size_t)b*128 + h] = o;
  }
}

// ---------- host ----------
extern "C" void kernel_launch(void* const* d_in, const int* in_sizes, int n_in,
                              void* d_out, int out_size, void* d_ws, size_t ws_size,
                              hipStream_t stream)
{
  (void)in_sizes; (void)n_in; (void)out_size; (void)ws_size;
  const float* x      = (const float*)d_in[0];
  const float* Wq     = (const float*)d_in[1];
  const float* bq     = (const float*)d_in[2];
  const float* Wk     = (const float*)d_in[3];
  const float* bk     = (const float*)d_in[4];
  const float* phi_w1 = (const float*)d_in[5];
  const float* phi_b1 = (const float*)d_in[6];
  const float* phi_w2 = (const float*)d_in[7];
  const float* phi_b2 = (const float*)d_in[8];
  const float* xi_w1  = (const float*)d_in[9];
  const float* xi_b1  = (const float*)d_in[10];
  const float* xi_w2  = (const float*)d_in[11];
  const float* xi_b2  = (const float*)d_in[12];
  const float* rho_w1 = (const float*)d_in[13];
  const float* rho_b1 = (const float*)d_in[14];
  const float* rho_w2 = (const float*)d_in[15];
  const float* rho_b2 = (const float*)d_in[16];
  float* out = (float*)d_out;

  float* M      = (float*)d_ws;                          // 4096
  float* uvc    = M + 4096;                              // 256 (129 used)
  float* y      = uvc + 256;                             // 512*256*64
  float* st     = y + (size_t)B_TOT*L_SEQ*D_IN;          // 2*512*256
  float* cand_v = st + (size_t)2*B_TOT*L_SEQ;            // 512*4*128
  int*   cand_i = (int*)(cand_v + (size_t)B_TOT*4*TOPK); // 512*4*128
  int*   selidx = cand_i + (size_t)B_TOT*4*TOPK;         // 512*128
  float* selw   = (float*)(selidx + (size_t)B_TOT*TOPK); // 512*128
  u8*    padm   = (u8*)(selw + (size_t)B_TOT*TOPK);      // 512*256

  k_prep <<<dim3(64),        dim3(256), 0, stream>>>(Wq, bq, Wk, bk, M, uvc);
  k_y    <<<dim3(4, B_TOT),  dim3(256), 0, stream>>>(x, M, uvc, y, st, padm);
  k_score<<<dim3(4, B_TOT),  dim3(256), 0, stream>>>(y, x, st, padm, cand_v, cand_i);
  k_merge<<<dim3(B_TOT),     dim3(256), 0, stream>>>(cand_v, cand_i, selidx, selw);
  k_mlp  <<<dim3(B_TOT),     dim3(256), 0, stream>>>(x, selidx, selw,
            phi_w1, phi_b1, phi_w2, phi_b2,
            xi_w1, xi_b1, xi_w2, xi_b2,
            rho_w1, rho_b1, rho_w2, rho_b2, out);
}

// Round 3
// 498.750 us; speedup vs baseline: 1.4368x; 1.4368x over previous
//
#include <hip/hip_runtime.h>

typedef unsigned short u16;
typedef unsigned int   u32;
typedef unsigned char  u8;

#define B_TOT 512
#define L_SEQ 256
#define D_IN  64
#define HIDN  256
#define TOPK  128
#define CAP   160              // candidate cap per wave-tile
#define NWT   32               // wave-tiles per batch: 4 rb x 2 cb x 4 waves

typedef float  f32x4  __attribute__((ext_vector_type(4)));
typedef __bf16 bf16x8 __attribute__((ext_vector_type(8)));

// ---------- helpers ----------
__device__ __forceinline__ u16 f2bf(float f){
  u32 u = __float_as_uint(f);
  u32 r = u + 0x7fffu + ((u>>16)&1u);   // RNE
  return (u16)(r>>16);
}
// monotonic float->uint key (descending float order == descending uint order)
__device__ __forceinline__ u32 sortKey(float f){
  u32 b = __float_as_uint(f);
  return (b & 0x80000000u) ? ~b : (b | 0x80000000u);
}
__device__ __forceinline__ float unKey(u32 u){
  u32 b = (u & 0x80000000u) ? (u & 0x7fffffffu) : ~u;
  return __uint_as_float(b);
}
__device__ __forceinline__ void cvt8(const float* v, u32* hp, u32* lp){
  #pragma unroll
  for (int i=0;i<4;++i){
    float v0 = v[2*i], v1 = v[2*i+1];
    u16 h0 = f2bf(v0); float h0f = __uint_as_float(((u32)h0)<<16); u16 l0 = f2bf(v0 - h0f);
    u16 h1 = f2bf(v1); float h1f = __uint_as_float(((u32)h1)<<16); u16 l1 = f2bf(v1 - h1f);
    hp[i] = (u32)h0 | ((u32)h1<<16);
    lp[i] = (u32)l0 | ((u32)l1<<16);
  }
}

// ---------- K0: M = Wq Wk^T (64x64), u = Wq bk, v = Wk bq, c = bq.bk ----------
__global__ __launch_bounds__(256) void k_prep(
    const float* __restrict__ Wq, const float* __restrict__ bq,
    const float* __restrict__ Wk, const float* __restrict__ bk,
    float* __restrict__ M, float* __restrict__ uvc)
{
  __shared__ float wq[HIDN];
  __shared__ float part[256];
  int a = blockIdx.x, tid = threadIdx.x;
  wq[tid] = Wq[a*HIDN + tid];
  __syncthreads();
  int bcol = tid & 63, q = tid >> 6;
  float s = 0.f;
  for (int h = q*64; h < q*64 + 64; ++h)
    s = fmaf(wq[h], Wk[bcol*HIDN + h], s);
  part[tid] = s;
  __syncthreads();
  if (tid < 64)
    M[a*64 + tid] = part[tid] + part[64+tid] + part[128+tid] + part[192+tid];
  if (tid == 0){
    float su = 0.f;
    for (int h=0; h<HIDN; ++h) su = fmaf(wq[h], bk[h], su);
    uvc[a] = su;
  }
  if (tid == 1){
    float sv = 0.f;
    for (int h=0; h<HIDN; ++h) sv = fmaf(Wk[a*HIDN + h], bq[h], sv);
    uvc[64 + a] = sv;
  }
  if (a == 0 && tid == 2){
    float c = 0.f;
    for (int h=0; h<HIDN; ++h) c = fmaf(bq[h], bk[h], c);
    uvc[128] = c;
  }
}

// ---------- K1: fused y=xM, scores = (yx^T + s_i + t_j)/16, per-wave top-k superset ----------
// grid dim3(2 cb, 4 rb, B): block tile = 64 rows x 128 cols; block 256
__global__ __launch_bounds__(256) void k_score(
    const float* __restrict__ x, const float* __restrict__ Mg,
    const float* __restrict__ uvc,
    u32* __restrict__ cand_k, int* __restrict__ cand_i, int* __restrict__ cand_n)
{
  __shared__ __align__(16) u16 Ubuf[2*128*72];   // phase A: Xr[64][68] f32 + Ms[64][68] f32 ; phase B: Bh/Bl [128][72] u16
  __shared__ __align__(16) u16 Ah[64][72];
  __shared__ __align__(16) u16 Al[64][72];
  __shared__ float sRow[64];
  __shared__ float tCol[128];
  __shared__ u8 padR[64], padC[128];

  float* Uf = (float*)Ubuf;
  float* Xr = Uf;              // [64][68]
  float* Ms = Uf + 64*68;      // [64][68]
  u16* Bh = Ubuf;              // [128][72]
  u16* Bl = Ubuf + 128*72;     // [128][72]

  int tid = threadIdx.x;
  int cb = blockIdx.x, rb = blockIdx.y, b = blockIdx.z;
  int r0 = rb*64, j0 = cb*128;
  const float* xb = x + (size_t)b*(L_SEQ*D_IN);

  // Phase A: stage Xr (block's 64 rows) and Ms (global M)
  {
    int r = tid >> 2, q = tid & 3;
    const float* sx = xb + (size_t)(r0 + r)*D_IN + q*16;
    const float* sm = Mg + r*D_IN + q*16;
    #pragma unroll
    for (int i=0;i<4;++i){
      *(float4*)&Xr[r*68 + q*16 + i*4] = *(const float4*)(sx + i*4);
      *(float4*)&Ms[r*68 + q*16 + i*4] = *(const float4*)(sm + i*4);
    }
  }
  // s_i, t_j, pad (reads global x directly; independent of LDS)
  if (tid < 128){
    int j = j0 + tid;
    const float* xj = xb + (size_t)j*D_IN;
    float tv = 0.f, pa = 0.f;
    #pragma unroll 8
    for (int a=0;a<64;++a){ float xa = xj[a]; tv = fmaf(xa, uvc[64+a], tv); pa += fabsf(xa); }
    tCol[tid] = tv; padC[tid] = (pa != 0.f) ? 1 : 0;
  } else if (tid < 192){
    int i = r0 + (tid - 128);
    const float* xi = xb + (size_t)i*D_IN;
    float sv = uvc[128], pa = 0.f;
    #pragma unroll 8
    for (int a=0;a<64;++a){ float xa = xi[a]; sv = fmaf(xa, uvc[a], sv); pa += fabsf(xa); }
    sRow[tid-128] = sv; padR[tid-128] = (pa != 0.f) ? 1 : 0;
  }
  __syncthreads();

  // y = Xr * Ms (f32), 16 outputs per thread
  float yv[16];
  {
    int r = tid >> 2, g = tid & 3;
    #pragma unroll
    for (int i=0;i<16;++i) yv[i] = 0.f;
    for (int a=0;a<64;++a){
      float xa = Xr[r*68 + a];
      #pragma unroll
      for (int c4=0;c4<4;++c4){
        float4 m4 = *(const float4*)&Ms[a*68 + g*16 + c4*4];
        yv[c4*4+0] = fmaf(xa, m4.x, yv[c4*4+0]);
        yv[c4*4+1] = fmaf(xa, m4.y, yv[c4*4+1]);
        yv[c4*4+2] = fmaf(xa, m4.z, yv[c4*4+2]);
        yv[c4*4+3] = fmaf(xa, m4.w, yv[c4*4+3]);
      }
    }
  }
  __syncthreads();   // all Xr/Ms reads done; Ubuf reusable

  // write split y -> Ah/Al (A-operand layout [row][k])
  {
    int r = tid >> 2, g = tid & 3;
    u32 hp[8], lp[8];
    cvt8(&yv[0], &hp[0], &lp[0]);
    cvt8(&yv[8], &hp[4], &lp[4]);
    *(uint4*)&Ah[r][g*16+0] = make_uint4(hp[0],hp[1],hp[2],hp[3]);
    *(uint4*)&Ah[r][g*16+8] = make_uint4(hp[4],hp[5],hp[6],hp[7]);
    *(uint4*)&Al[r][g*16+0] = make_uint4(lp[0],lp[1],lp[2],lp[3]);
    *(uint4*)&Al[r][g*16+8] = make_uint4(lp[4],lp[5],lp[6],lp[7]);
  }
  // stage split x cols -> Bh/Bl (B^T layout [col][k])
  {
    int col = tid >> 1, hf = tid & 1;
    const float* src = xb + (size_t)(j0 + col)*D_IN + hf*32;
    #pragma unroll
    for (int q=0;q<2;++q){
      float vv[16];
      #pragma unroll
      for (int i=0;i<4;++i)
        *(float4*)&vv[i*4] = *(const float4*)(src + q*16 + i*4);
      u32 hp[8], lp[8];
      cvt8(&vv[0], &hp[0], &lp[0]);
      cvt8(&vv[8], &hp[4], &lp[4]);
      *(uint4*)&Bh[col*72 + hf*32 + q*16 + 0] = make_uint4(hp[0],hp[1],hp[2],hp[3]);
      *(uint4*)&Bh[col*72 + hf*32 + q*16 + 8] = make_uint4(hp[4],hp[5],hp[6],hp[7]);
      *(uint4*)&Bl[col*72 + hf*32 + q*16 + 0] = make_uint4(lp[0],lp[1],lp[2],lp[3]);
      *(uint4*)&Bl[col*72 + hf*32 + q*16 + 8] = make_uint4(lp[4],lp[5],lp[6],lp[7]);
    }
  }
  __syncthreads();   // frags ready; NO barriers after this point

  int w = tid >> 6, lane = tid & 63;
  int lm = lane & 15, quad = lane >> 4;
  bf16x8 A_h0 = *(const bf16x8*)&Ah[w*16+lm][quad*8];
  bf16x8 A_h1 = *(const bf16x8*)&Ah[w*16+lm][32 + quad*8];
  bf16x8 A_l0 = *(const bf16x8*)&Al[w*16+lm][quad*8];
  bf16x8 A_l1 = *(const bf16x8*)&Al[w*16+lm][32 + quad*8];
  float sr4[4]; u32 prb[4];
  #pragma unroll
  for (int r=0;r<4;++r){
    sr4[r] = sRow[w*16 + quad*4 + r];
    prb[r] = padR[w*16 + quad*4 + r];
  }
  const float NINF = __uint_as_float(0xff800000u);
  float av[32];   // holds sortKey bits

  #pragma unroll
  for (int ct=0; ct<8; ++ct){
    const u16* bp = &Bh[(ct*16+lm)*72];
    const u16* blo = &Bl[(ct*16+lm)*72];
    bf16x8 B_h0 = *(const bf16x8*)(bp + quad*8);
    bf16x8 B_h1 = *(const bf16x8*)(bp + 32 + quad*8);
    bf16x8 B_l0 = *(const bf16x8*)(blo + quad*8);
    bf16x8 B_l1 = *(const bf16x8*)(blo + 32 + quad*8);
    f32x4 acc = {0.f,0.f,0.f,0.f};
    acc = __builtin_amdgcn_mfma_f32_16x16x32_bf16(A_h0, B_h0, acc, 0,0,0);
    acc = __builtin_amdgcn_mfma_f32_16x16x32_bf16(A_h1, B_h1, acc, 0,0,0);
    acc = __builtin_amdgcn_mfma_f32_16x16x32_bf16(A_l0, B_h0, acc, 0,0,0);
    acc = __builtin_amdgcn_mfma_f32_16x16x32_bf16(A_l1, B_h1, acc, 0,0,0);
    acc = __builtin_amdgcn_mfma_f32_16x16x32_bf16(A_h0, B_l0, acc, 0,0,0);
    acc = __builtin_amdgcn_mfma_f32_16x16x32_bf16(A_h1, B_l1, acc, 0,0,0);
    float tc = tCol[ct*16 + lm];
    bool pc = padC[ct*16 + lm] != 0;
    #pragma unroll
    for (int r=0;r<4;++r){
      bool ok = pc && (prb[r] != 0);
      float v = ok ? (acc[r] + sr4[r] + tc)*0.0625f : NINF;
      av[ct*4 + r] = __uint_as_float(sortKey(v));
    }
  }

  // per-wave 16-bit-prefix threshold: max T16 with count(key16 >= T16) >= 128
  u32 T = 0;
  for (int bit=15; bit>=0; --bit){
    u32 thr = (T | (1u<<bit)) << 16;
    int c = 0;
    #pragma unroll
    for (int i=0;i<32;++i) c += (__float_as_uint(av[i]) >= thr) ? 1 : 0;
    #pragma unroll
    for (int off=1; off<64; off<<=1) c += __shfl_xor(c, off);
    if (c >= TOPK) T |= (1u<<bit);
  }
  u32 thr = T << 16;

  // emit all keys >= thr (superset of wave-tile top-128), lane-prefix order
  int myc = 0;
  #pragma unroll
  for (int i=0;i<32;++i) myc += (__float_as_uint(av[i]) >= thr) ? 1 : 0;
  int pre = myc;
  #pragma unroll
  for (int off=1; off<64; off<<=1){
    int n = __shfl_up(pre, off);
    if (lane >= off) pre += n;
  }
  int total = __shfl(pre, 63);
  int pos = pre - myc;      // exclusive prefix
  int wt = (rb*2 + cb)*4 + w;
  size_t base = ((size_t)b*NWT + wt)*CAP;
  if (lane == 0) cand_n[b*NWT + wt] = (total < CAP) ? total : CAP;
  #pragma unroll
  for (int i=0;i<32;++i){
    u32 u = __float_as_uint(av[i]);
    if (u >= thr && pos < CAP){
      int r = i & 3, ct = i >> 2;
      int row = r0 + w*16 + quad*4 + r;
      int col = j0 + ct*16 + lm;
      cand_k[base + pos] = u;
      cand_i[base + pos] = row*L_SEQ + col;
      ++pos;
    }
  }
}

// ---------- K2: exact merge of <=32x160 candidates -> top-128 + softmax ----------
__global__ __launch_bounds__(256) void k_merge(
    const u32* __restrict__ cand_k, const int* __restrict__ cand_i, const int* __restrict__ cand_n,
    int* __restrict__ selidx, float* __restrict__ selw)
{
  __shared__ int red32[34];
  __shared__ int cnts[NWT];
  __shared__ int cm, eqc;
  __shared__ int eqi[256];
  __shared__ float sv[TOPK]; __shared__ int si[TOPK];
  __shared__ float fred[8];
  int b = blockIdx.x, tid = threadIdx.x;
  const int NS = NWT*CAP/256;   // 20
  if (tid < NWT) cnts[tid] = cand_n[b*NWT + tid];
  if (tid < 34) red32[tid] = 0;
  if (tid == 0){ cm = 0; eqc = 0; }
  __syncthreads();

  u32 key[NS]; int idx[NS];
  size_t bb = (size_t)b*NWT*CAP;
  #pragma unroll
  for (int s=0;s<NS;++s){
    int e = tid + 256*s;
    int slot = e / CAP, p = e - slot*CAP;
    bool ok = p < cnts[slot];
    key[s] = ok ? cand_k[bb + e] : 0u;
    idx[s] = ok ? cand_i[bb + e] : 0x7fffffff;
  }

  u32 T = 0;
  for (int bit=31; bit>=0; --bit){
    u32 c2 = T | (1u<<bit);
    int c = 0;
    #pragma unroll
    for (int s=0;s<NS;++s) c += (key[s] >= c2) ? 1 : 0;
    #pragma unroll
    for (int off=1; off<64; off<<=1) c += __shfl_xor(c, off);
    if ((tid&63)==0) atomicAdd(&red32[31-bit], c);
    __syncthreads();
    if (red32[31-bit] >= TOPK) T = c2;
  }
  {
    int c = 0;
    #pragma unroll
    for (int s=0;s<NS;++s) c += (key[s] > T) ? 1 : 0;
    #pragma unroll
    for (int off=1; off<64; off<<=1) c += __shfl_xor(c, off);
    if ((tid&63)==0) atomicAdd(&red32[33], c);
  }
  __syncthreads();
  int m = red32[33];

  #pragma unroll
  for (int s=0;s<NS;++s){
    if (key[s] > T){
      int p = atomicAdd(&cm, 1);
      sv[p] = unKey(key[s]); si[p] = idx[s];
    } else if (key[s] == T && key[s] != 0u){
      int q = atomicAdd(&eqc, 1);
      if (q < 256) eqi[q] = idx[s];
    }
  }
  __syncthreads();
  if (tid == 0){
    int need = TOPK - m;
    int n = eqc < 256 ? eqc : 256;
    float tv = unKey(T);
    for (int s2=0; s2<need; ++s2){
      int bi = s2;
      for (int j=s2+1;j<n;++j) if (eqi[j] < eqi[bi]) bi = j;
      int t2 = eqi[s2]; eqi[s2] = eqi[bi]; eqi[bi] = t2;
      sv[m+s2] = tv; si[m+s2] = eqi[s2];
    }
  }
  __syncthreads();

  // parallel softmax over sv[128]
  float v = (tid < TOPK) ? sv[tid] : -3.4e38f;
  float mx = v;
  #pragma unroll
  for (int off=1; off<64; off<<=1) mx = fmaxf(mx, __shfl_xor(mx, off));
  if ((tid&63)==0) fred[tid>>6] = mx;
  __syncthreads();
  mx = fmaxf(fred[0], fred[1]);
  float e = (tid < TOPK) ? expf(v - mx) : 0.f;
  float s = e;
  #pragma unroll
  for (int off=1; off<64; off<<=1) s += __shfl_xor(s, off);
  if ((tid&63)==0) fred[4 + (tid>>6)] = s;
  __syncthreads();
  s = fred[4] + fred[5];
  if (tid < TOPK){
    selw[(size_t)b*TOPK + tid]   = e / s;
    selidx[(size_t)b*TOPK + tid] = si[tid];
  }
}

// ---------- K3: gather + MLP1 + weighted pooling (layer2 fused) + rho ----------
__global__ __launch_bounds__(256) void k_mlp(
    const float* __restrict__ x, const int* __restrict__ selidx, const float* __restrict__ selw,
    const float* __restrict__ phi_w1, const float* __restrict__ phi_b1,
    const float* __restrict__ phi_w2, const float* __restrict__ phi_b2,
    const float* __restrict__ xi_w1,  const float* __restrict__ xi_b1,
    const float* __restrict__ xi_w2,  const float* __restrict__ xi_b2,
    const float* __restrict__ rho_w1, const float* __restrict__ rho_b1,
    const float* __restrict__ rho_w2, const float* __restrict__ rho_b2,
    float* __restrict__ out)
{
  __shared__ float sxc[64][128];
  __shared__ int   sidx[TOPK];
  __shared__ float swp[TOPK], swd[TOPK];
  __shared__ float gpL[256], gsL[256];
  __shared__ float pooled[256], t1[256];
  __shared__ float wsums[2];
  int b = blockIdx.x, h = threadIdx.x;

  if (h < TOPK){
    int fl = selidx[(size_t)b*TOPK + h];
    sidx[h] = fl;
    float w = selw[(size_t)b*TOPK + h];
    bool dg = ((fl>>8) == (fl&255));
    swp[h] = dg ? 0.f : w;
    swd[h] = dg ? w   : 0.f;
  }
  __syncthreads();
  if (h==0){
    float a=0.f,c=0.f;
    for (int k=0;k<TOPK;++k){ a+=swp[k]; c+=swd[k]; }
    wsums[0]=a; wsums[1]=c;
  }

  float gp=0.f, gs=0.f;
  float bxi = xi_b1[h];
  float bph = phi_b1[h];

  for (int tile=0; tile<2; ++tile){
    __syncthreads();
    for (int i=0;i<32;++i){
      int e = h + 256*i; int k = e>>7, d = e&127;
      int fl = sidx[tile*64+k];
      int rc = (d<64) ? (fl>>8) : (fl&255);
      sxc[k][d] = x[((size_t)b*L_SEQ + rc)*D_IN + (d&63)];
    }
    __syncthreads();
    for (int kb=0; kb<64; kb+=8){
      float acc[8];
      #pragma unroll
      for (int j=0;j<8;++j) acc[j]=bxi;
      #pragma unroll 4
      for (int d0=0; d0<128; d0+=4){
        float w0 = xi_w1[(d0+0)*HIDN + h];
        float w1 = xi_w1[(d0+1)*HIDN + h];
        float w2 = xi_w1[(d0+2)*HIDN + h];
        float w3 = xi_w1[(d0+3)*HIDN + h];
        #pragma unroll
        for (int j=0;j<8;++j){
          float4 xv = *(const float4*)&sxc[kb+j][d0];
          acc[j] = fmaf(xv.x,w0,fmaf(xv.y,w1,fmaf(xv.z,w2,fmaf(xv.w,w3,acc[j]))));
        }
      }
      #pragma unroll
      for (int j=0;j<8;++j)
        gp += swp[tile*64+kb+j]*fmaxf(acc[j],0.f);
    }
    for (int k=0;k<64;++k){
      float wd = swd[tile*64+k];
      if (wd != 0.f){
        float a = bph;
        #pragma unroll 4
        for (int d0=0; d0<64; d0+=4){
          float w0 = phi_w1[(d0+0)*HIDN + h];
          float w1 = phi_w1[(d0+1)*HIDN + h];
          float w2 = phi_w1[(d0+2)*HIDN + h];
          float w3 = phi_w1[(d0+3)*HIDN + h];
          float4 xv = *(const float4*)&sxc[k][d0];
          a = fmaf(xv.x,w0,fmaf(xv.y,w1,fmaf(xv.z,w2,fmaf(xv.w,w3,a))));
        }
        gs += wd*fmaxf(a,0.f);
      }
    }
  }
  gpL[h]=gp; gsL[h]=gs;
  __syncthreads();

  {
    float wsp=wsums[0], wss=wsums[1];
    float po = wsp*xi_b2[h] + wss*phi_b2[h];
    for (int d=0; d<256; ++d){
      po = fmaf(gpL[d], xi_w2[d*HIDN + h], po);
      po = fmaf(gsL[d], phi_w2[d*HIDN + h], po);
    }
    pooled[h]=po;
  }
  __syncthreads();
  {
    float a = rho_b1[h];
    for (int d=0; d<256; ++d) a = fmaf(pooled[d], rho_w1[d*HIDN + h], a);
    t1[h] = fmaxf(a,0.f);
  }
  __syncthreads();
  if (h < 128){
    float o = rho_b2[h];
    for (int d=0; d<256; ++d) o = fmaf(t1[d], rho_w2[d*128 + h], o);
    out[(size_t)b*128 + h] = o;
  }
}

// ---------- host ----------
extern "C" void kernel_launch(void* const* d_in, const int* in_sizes, int n_in,
                              void* d_out, int out_size, void* d_ws, size_t ws_size,
                              hipStream_t stream)
{
  (void)in_sizes; (void)n_in; (void)out_size; (void)ws_size;
  const float* x      = (const float*)d_in[0];
  const float* Wq     = (const float*)d_in[1];
  const float* bq     = (const float*)d_in[2];
  const float* Wk     = (const float*)d_in[3];
  const float* bk     = (const float*)d_in[4];
  const float* phi_w1 = (const float*)d_in[5];
  const float* phi_b1 = (const float*)d_in[6];
  const float* phi_w2 = (const float*)d_in[7];
  const float* phi_b2 = (const float*)d_in[8];
  const float* xi_w1  = (const float*)d_in[9];
  const float* xi_b1  = (const float*)d_in[10];
  const float* xi_w2  = (const float*)d_in[11];
  const float* xi_b2  = (const float*)d_in[12];
  const float* rho_w1 = (const float*)d_in[13];
  const float* rho_b1 = (const float*)d_in[14];
  const float* rho_w2 = (const float*)d_in[15];
  const float* rho_b2 = (const float*)d_in[16];
  float* out = (float*)d_out;

  float* M      = (float*)d_ws;                               // 4096
  float* uvc    = M + 4096;                                   // 256
  u32*   cand_k = (u32*)(uvc + 256);                          // 512*32*160
  int*   cand_i = (int*)(cand_k + (size_t)B_TOT*NWT*CAP);     // 512*32*160
  int*   cand_n = cand_i + (size_t)B_TOT*NWT*CAP;             // 512*32
  int*   selidx = cand_n + (size_t)B_TOT*NWT;                 // 512*128
  float* selw   = (float*)(selidx + (size_t)B_TOT*TOPK);      // 512*128

  k_prep <<<dim3(64),          dim3(256), 0, stream>>>(Wq, bq, Wk, bk, M, uvc);
  k_score<<<dim3(2, 4, B_TOT), dim3(256), 0, stream>>>(x, M, uvc, cand_k, cand_i, cand_n);
  k_merge<<<dim3(B_TOT),       dim3(256), 0, stream>>>(cand_k, cand_i, cand_n, selidx, selw);
  k_mlp  <<<dim3(B_TOT),       dim3(256), 0, stream>>>(x, selidx, selw,
            phi_w1, phi_b1, phi_w2, phi_b2,
            xi_w1, xi_b1, xi_w2, xi_b2,
            rho_w1, rho_b1, rho_w2, rho_b2, out);
}

// Round 4
// 367.826 us; speedup vs baseline: 1.9482x; 1.3559x over previous
//
#include <hip/hip_runtime.h>

typedef unsigned short u16;
typedef unsigned int   u32;
typedef unsigned char  u8;

#define B_TOT 512
#define L_SEQ 256
#define D_IN  64
#define HIDN  256
#define TOPK  128
#define CAP   160              // candidate cap per wave-tile
#define NWT   32               // wave-tiles per batch: 4 rb x 2 cb x 4 waves

typedef float  f32x4  __attribute__((ext_vector_type(4)));
typedef __bf16 bf16x8 __attribute__((ext_vector_type(8)));

// ---------- helpers ----------
__device__ __forceinline__ u16 f2bf(float f){
  u32 u = __float_as_uint(f);
  u32 r = u + 0x7fffu + ((u>>16)&1u);   // RNE
  return (u16)(r>>16);
}
// monotonic float->uint key (descending float order == descending uint order)
__device__ __forceinline__ u32 sortKey(float f){
  u32 b = __float_as_uint(f);
  return (b & 0x80000000u) ? ~b : (b | 0x80000000u);
}
__device__ __forceinline__ float unKey(u32 u){
  u32 b = (u & 0x80000000u) ? (u & 0x7fffffffu) : ~u;
  return __uint_as_float(b);
}
__device__ __forceinline__ void cvt8(const float* v, u32* hp, u32* lp){
  #pragma unroll
  for (int i=0;i<4;++i){
    float v0 = v[2*i], v1 = v[2*i+1];
    u16 h0 = f2bf(v0); float h0f = __uint_as_float(((u32)h0)<<16); u16 l0 = f2bf(v0 - h0f);
    u16 h1 = f2bf(v1); float h1f = __uint_as_float(((u32)h1)<<16); u16 l1 = f2bf(v1 - h1f);
    hp[i] = (u32)h0 | ((u32)h1<<16);
    lp[i] = (u32)l0 | ((u32)l1<<16);
  }
}

// ---------- K0: M = Wq Wk^T (64x64), u = Wq bk, v = Wk bq, c = bq.bk ----------
__global__ __launch_bounds__(256) void k_prep(
    const float* __restrict__ Wq, const float* __restrict__ bq,
    const float* __restrict__ Wk, const float* __restrict__ bk,
    float* __restrict__ M, float* __restrict__ uvc)
{
  __shared__ float wq[HIDN];
  __shared__ float part[256];
  int a = blockIdx.x, tid = threadIdx.x;
  wq[tid] = Wq[a*HIDN + tid];
  __syncthreads();
  int bcol = tid & 63, q = tid >> 6;
  float s = 0.f;
  for (int h = q*64; h < q*64 + 64; ++h)
    s = fmaf(wq[h], Wk[bcol*HIDN + h], s);
  part[tid] = s;
  __syncthreads();
  if (tid < 64)
    M[a*64 + tid] = part[tid] + part[64+tid] + part[128+tid] + part[192+tid];
  if (tid == 0){
    float su = 0.f;
    for (int h=0; h<HIDN; ++h) su = fmaf(wq[h], bk[h], su);
    uvc[a] = su;
  }
  if (tid == 1){
    float sv = 0.f;
    for (int h=0; h<HIDN; ++h) sv = fmaf(Wk[a*HIDN + h], bq[h], sv);
    uvc[64 + a] = sv;
  }
  if (a == 0 && tid == 2){
    float c = 0.f;
    for (int h=0; h<HIDN; ++h) c = fmaf(bq[h], bk[h], c);
    uvc[128] = c;
  }
}

// ---------- K0b: split+transpose MLP layer-1 weights into [h][d] hi/lo bf16 ----------
// grid 192 x 256: first 32768 threads xi (256h x 128d), next 16384 phi (256h x 64d)
__global__ __launch_bounds__(256) void k_split(
    const float* __restrict__ xi_w1, const float* __restrict__ phi_w1,
    u16* __restrict__ xiH, u16* __restrict__ xiL,
    u16* __restrict__ phiH, u16* __restrict__ phiL)
{
  int t = blockIdx.x*256 + threadIdx.x;
  if (t < 256*128){
    int h = t >> 7, d = t & 127;
    float v = xi_w1[d*HIDN + h];
    u16 hh = f2bf(v); float hf = __uint_as_float(((u32)hh)<<16);
    u16 ll = f2bf(v - hf);
    xiH[h*128 + d] = hh; xiL[h*128 + d] = ll;
  } else {
    int t2 = t - 256*128;
    int h = t2 >> 6, d = t2 & 63;
    float v = phi_w1[d*HIDN + h];
    u16 hh = f2bf(v); float hf = __uint_as_float(((u32)hh)<<16);
    u16 ll = f2bf(v - hf);
    phiH[h*64 + d] = hh; phiL[h*64 + d] = ll;
  }
}

// ---------- K1: fused y=xM, scores = (yx^T + s_i + t_j)/16, per-wave top-k superset ----------
// grid dim3(2 cb, 4 rb, B): block tile = 64 rows x 128 cols; block 256
__global__ __launch_bounds__(256) void k_score(
    const float* __restrict__ x, const float* __restrict__ Mg,
    const float* __restrict__ uvc,
    u32* __restrict__ cand_k, int* __restrict__ cand_i, int* __restrict__ cand_n)
{
  __shared__ __align__(16) u16 Ubuf[2*128*72];
  __shared__ __align__(16) u16 Ah[64][72];
  __shared__ __align__(16) u16 Al[64][72];
  __shared__ float sRow[64];
  __shared__ float tCol[128];
  __shared__ u8 padR[64], padC[128];

  float* Uf = (float*)Ubuf;
  float* Xr = Uf;              // [64][68]
  float* Ms = Uf + 64*68;      // [64][68]
  u16* Bh = Ubuf;              // [128][72]
  u16* Bl = Ubuf + 128*72;     // [128][72]

  int tid = threadIdx.x;
  int cb = blockIdx.x, rb = blockIdx.y, b = blockIdx.z;
  int r0 = rb*64, j0 = cb*128;
  const float* xb = x + (size_t)b*(L_SEQ*D_IN);

  {
    int r = tid >> 2, q = tid & 3;
    const float* sx = xb + (size_t)(r0 + r)*D_IN + q*16;
    const float* sm = Mg + r*D_IN + q*16;
    #pragma unroll
    for (int i=0;i<4;++i){
      *(float4*)&Xr[r*68 + q*16 + i*4] = *(const float4*)(sx + i*4);
      *(float4*)&Ms[r*68 + q*16 + i*4] = *(const float4*)(sm + i*4);
    }
  }
  if (tid < 128){
    int j = j0 + tid;
    const float* xj = xb + (size_t)j*D_IN;
    float tv = 0.f, pa = 0.f;
    #pragma unroll 8
    for (int a=0;a<64;++a){ float xa = xj[a]; tv = fmaf(xa, uvc[64+a], tv); pa += fabsf(xa); }
    tCol[tid] = tv; padC[tid] = (pa != 0.f) ? 1 : 0;
  } else if (tid < 192){
    int i = r0 + (tid - 128);
    const float* xi = xb + (size_t)i*D_IN;
    float sv = uvc[128], pa = 0.f;
    #pragma unroll 8
    for (int a=0;a<64;++a){ float xa = xi[a]; sv = fmaf(xa, uvc[a], sv); pa += fabsf(xa); }
    sRow[tid-128] = sv; padR[tid-128] = (pa != 0.f) ? 1 : 0;
  }
  __syncthreads();

  float yv[16];
  {
    int r = tid >> 2, g = tid & 3;
    #pragma unroll
    for (int i=0;i<16;++i) yv[i] = 0.f;
    for (int a=0;a<64;++a){
      float xa = Xr[r*68 + a];
      #pragma unroll
      for (int c4=0;c4<4;++c4){
        float4 m4 = *(const float4*)&Ms[a*68 + g*16 + c4*4];
        yv[c4*4+0] = fmaf(xa, m4.x, yv[c4*4+0]);
        yv[c4*4+1] = fmaf(xa, m4.y, yv[c4*4+1]);
        yv[c4*4+2] = fmaf(xa, m4.z, yv[c4*4+2]);
        yv[c4*4+3] = fmaf(xa, m4.w, yv[c4*4+3]);
      }
    }
  }
  __syncthreads();

  {
    int r = tid >> 2, g = tid & 3;
    u32 hp[8], lp[8];
    cvt8(&yv[0], &hp[0], &lp[0]);
    cvt8(&yv[8], &hp[4], &lp[4]);
    *(uint4*)&Ah[r][g*16+0] = make_uint4(hp[0],hp[1],hp[2],hp[3]);
    *(uint4*)&Ah[r][g*16+8] = make_uint4(hp[4],hp[5],hp[6],hp[7]);
    *(uint4*)&Al[r][g*16+0] = make_uint4(lp[0],lp[1],lp[2],lp[3]);
    *(uint4*)&Al[r][g*16+8] = make_uint4(lp[4],lp[5],lp[6],lp[7]);
  }
  {
    int col = tid >> 1, hf = tid & 1;
    const float* src = xb + (size_t)(j0 + col)*D_IN + hf*32;
    #pragma unroll
    for (int q=0;q<2;++q){
      float vv[16];
      #pragma unroll
      for (int i=0;i<4;++i)
        *(float4*)&vv[i*4] = *(const float4*)(src + q*16 + i*4);
      u32 hp[8], lp[8];
      cvt8(&vv[0], &hp[0], &lp[0]);
      cvt8(&vv[8], &hp[4], &lp[4]);
      *(uint4*)&Bh[col*72 + hf*32 + q*16 + 0] = make_uint4(hp[0],hp[1],hp[2],hp[3]);
      *(uint4*)&Bh[col*72 + hf*32 + q*16 + 8] = make_uint4(hp[4],hp[5],hp[6],hp[7]);
      *(uint4*)&Bl[col*72 + hf*32 + q*16 + 0] = make_uint4(lp[0],lp[1],lp[2],lp[3]);
      *(uint4*)&Bl[col*72 + hf*32 + q*16 + 8] = make_uint4(lp[4],lp[5],lp[6],lp[7]);
    }
  }
  __syncthreads();

  int w = tid >> 6, lane = tid & 63;
  int lm = lane & 15, quad = lane >> 4;
  bf16x8 A_h0 = *(const bf16x8*)&Ah[w*16+lm][quad*8];
  bf16x8 A_h1 = *(const bf16x8*)&Ah[w*16+lm][32 + quad*8];
  bf16x8 A_l0 = *(const bf16x8*)&Al[w*16+lm][quad*8];
  bf16x8 A_l1 = *(const bf16x8*)&Al[w*16+lm][32 + quad*8];
  float sr4[4]; u32 prb[4];
  #pragma unroll
  for (int r=0;r<4;++r){
    sr4[r] = sRow[w*16 + quad*4 + r];
    prb[r] = padR[w*16 + quad*4 + r];
  }
  const float NINF = __uint_as_float(0xff800000u);
  float av[32];

  #pragma unroll
  for (int ct=0; ct<8; ++ct){
    const u16* bp = &Bh[(ct*16+lm)*72];
    const u16* blo = &Bl[(ct*16+lm)*72];
    bf16x8 B_h0 = *(const bf16x8*)(bp + quad*8);
    bf16x8 B_h1 = *(const bf16x8*)(bp + 32 + quad*8);
    bf16x8 B_l0 = *(const bf16x8*)(blo + quad*8);
    bf16x8 B_l1 = *(const bf16x8*)(blo + 32 + quad*8);
    f32x4 acc = {0.f,0.f,0.f,0.f};
    acc = __builtin_amdgcn_mfma_f32_16x16x32_bf16(A_h0, B_h0, acc, 0,0,0);
    acc = __builtin_amdgcn_mfma_f32_16x16x32_bf16(A_h1, B_h1, acc, 0,0,0);
    acc = __builtin_amdgcn_mfma_f32_16x16x32_bf16(A_l0, B_h0, acc, 0,0,0);
    acc = __builtin_amdgcn_mfma_f32_16x16x32_bf16(A_l1, B_h1, acc, 0,0,0);
    acc = __builtin_amdgcn_mfma_f32_16x16x32_bf16(A_h0, B_l0, acc, 0,0,0);
    acc = __builtin_amdgcn_mfma_f32_16x16x32_bf16(A_h1, B_l1, acc, 0,0,0);
    float tc = tCol[ct*16 + lm];
    bool pc = padC[ct*16 + lm] != 0;
    #pragma unroll
    for (int r=0;r<4;++r){
      bool ok = pc && (prb[r] != 0);
      float v = ok ? (acc[r] + sr4[r] + tc)*0.0625f : NINF;
      av[ct*4 + r] = __uint_as_float(sortKey(v));
    }
  }

  u32 T = 0;
  for (int bit=15; bit>=0; --bit){
    u32 thr = (T | (1u<<bit)) << 16;
    int c = 0;
    #pragma unroll
    for (int i=0;i<32;++i) c += (__float_as_uint(av[i]) >= thr) ? 1 : 0;
    #pragma unroll
    for (int off=1; off<64; off<<=1) c += __shfl_xor(c, off);
    if (c >= TOPK) T |= (1u<<bit);
  }
  u32 thr = T << 16;

  int myc = 0;
  #pragma unroll
  for (int i=0;i<32;++i) myc += (__float_as_uint(av[i]) >= thr) ? 1 : 0;
  int pre = myc;
  #pragma unroll
  for (int off=1; off<64; off<<=1){
    int n = __shfl_up(pre, off);
    if (lane >= off) pre += n;
  }
  int total = __shfl(pre, 63);
  int pos = pre - myc;
  int wt = (rb*2 + cb)*4 + w;
  size_t base = ((size_t)b*NWT + wt)*CAP;
  if (lane == 0) cand_n[b*NWT + wt] = (total < CAP) ? total : CAP;
  #pragma unroll
  for (int i=0;i<32;++i){
    u32 u = __float_as_uint(av[i]);
    if (u >= thr && pos < CAP){
      int r = i & 3, ct = i >> 2;
      int row = r0 + w*16 + quad*4 + r;
      int col = j0 + ct*16 + lm;
      cand_k[base + pos] = u;
      cand_i[base + pos] = row*L_SEQ + col;
      ++pos;
    }
  }
}

// ---------- K2: exact merge of <=32x160 candidates -> top-128 + softmax ----------
__global__ __launch_bounds__(256) void k_merge(
    const u32* __restrict__ cand_k, const int* __restrict__ cand_i, const int* __restrict__ cand_n,
    int* __restrict__ selidx, float* __restrict__ selw)
{
  __shared__ int red32[34];
  __shared__ int cnts[NWT];
  __shared__ int cm, eqc;
  __shared__ int eqi[256];
  __shared__ float sv[TOPK]; __shared__ int si[TOPK];
  __shared__ float fred[8];
  int b = blockIdx.x, tid = threadIdx.x;
  const int NS = NWT*CAP/256;   // 20
  if (tid < NWT) cnts[tid] = cand_n[b*NWT + tid];
  if (tid < 34) red32[tid] = 0;
  if (tid == 0){ cm = 0; eqc = 0; }
  __syncthreads();

  u32 key[NS]; int idx[NS];
  size_t bb = (size_t)b*NWT*CAP;
  #pragma unroll
  for (int s=0;s<NS;++s){
    int e = tid + 256*s;
    int slot = e / CAP, p = e - slot*CAP;
    bool ok = p < cnts[slot];
    key[s] = ok ? cand_k[bb + e] : 0u;
    idx[s] = ok ? cand_i[bb + e] : 0x7fffffff;
  }

  u32 T = 0;
  for (int bit=31; bit>=0; --bit){
    u32 c2 = T | (1u<<bit);
    int c = 0;
    #pragma unroll
    for (int s=0;s<NS;++s) c += (key[s] >= c2) ? 1 : 0;
    #pragma unroll
    for (int off=1; off<64; off<<=1) c += __shfl_xor(c, off);
    if ((tid&63)==0) atomicAdd(&red32[31-bit], c);
    __syncthreads();
    if (red32[31-bit] >= TOPK) T = c2;
  }
  {
    int c = 0;
    #pragma unroll
    for (int s=0;s<NS;++s) c += (key[s] > T) ? 1 : 0;
    #pragma unroll
    for (int off=1; off<64; off<<=1) c += __shfl_xor(c, off);
    if ((tid&63)==0) atomicAdd(&red32[33], c);
  }
  __syncthreads();
  int m = red32[33];

  #pragma unroll
  for (int s=0;s<NS;++s){
    if (key[s] > T){
      int p = atomicAdd(&cm, 1);
      sv[p] = unKey(key[s]); si[p] = idx[s];
    } else if (key[s] == T && key[s] != 0u){
      int q = atomicAdd(&eqc, 1);
      if (q < 256) eqi[q] = idx[s];
    }
  }
  __syncthreads();
  if (tid == 0){
    int need = TOPK - m;
    int n = eqc < 256 ? eqc : 256;
    float tv = unKey(T);
    for (int s2=0; s2<need; ++s2){
      int bi = s2;
      for (int j=s2+1;j<n;++j) if (eqi[j] < eqi[bi]) bi = j;
      int t2 = eqi[s2]; eqi[s2] = eqi[bi]; eqi[bi] = t2;
      sv[m+s2] = tv; si[m+s2] = eqi[s2];
    }
  }
  __syncthreads();

  float v = (tid < TOPK) ? sv[tid] : -3.4e38f;
  float mx = v;
  #pragma unroll
  for (int off=1; off<64; off<<=1) mx = fmaxf(mx, __shfl_xor(mx, off));
  if ((tid&63)==0) fred[tid>>6] = mx;
  __syncthreads();
  mx = fmaxf(fred[0], fred[1]);
  float e = (tid < TOPK) ? expf(v - mx) : 0.f;
  float s = e;
  #pragma unroll
  for (int off=1; off<64; off<<=1) s += __shfl_xor(s, off);
  if ((tid&63)==0) fred[4 + (tid>>6)] = s;
  __syncthreads();
  s = fred[4] + fred[5];
  if (tid < TOPK){
    selw[(size_t)b*TOPK + tid]   = e / s;
    selidx[(size_t)b*TOPK + tid] = si[tid];
  }
}

// ---------- K3: gather + split-bf16 MFMA MLP1 + weighted pooling (layer2 fused) + rho ----------
// grid B_TOT (batch), block 256 (4 waves). A-frags stored in MFMA fragment order in LDS.
__global__ __launch_bounds__(256) void k_mlp(
    const float* __restrict__ x, const int* __restrict__ selidx, const float* __restrict__ selw,
    const u16* __restrict__ xiH, const u16* __restrict__ xiL,
    const u16* __restrict__ phiH, const u16* __restrict__ phiL,
    const float* __restrict__ phi_b1, const float* __restrict__ phi_w2, const float* __restrict__ phi_b2,
    const float* __restrict__ xi_b1,  const float* __restrict__ xi_w2,  const float* __restrict__ xi_b2,
    const float* __restrict__ rho_w1, const float* __restrict__ rho_b1,
    const float* __restrict__ rho_w2, const float* __restrict__ rho_b2,
    float* __restrict__ out)
{
  __shared__ __align__(16) u16 AFh[8][4][64][8];   // [ktile][kchunk][lane][j] 32KB
  __shared__ __align__(16) u16 AFl[8][4][64][8];   // 32KB
  __shared__ int   sidx[TOPK];
  __shared__ float swp[TOPK], swd[TOPK];
  __shared__ float gpL[256], gsL[256];
  __shared__ float pooled[256], t1[256];
  __shared__ float wsums[2];
  int b = blockIdx.x, tid = threadIdx.x;

  if (tid < TOPK){
    int fl = selidx[(size_t)b*TOPK + tid];
    sidx[tid] = fl;
    float wv = selw[(size_t)b*TOPK + tid];
    bool dg = ((fl>>8) == (fl&255));
    swp[tid] = dg ? 0.f : wv;
    swd[tid] = dg ? wv  : 0.f;
  }
  __syncthreads();
  if (tid == 0){
    float a=0.f, c2=0.f;
    for (int k=0;k<TOPK;++k){ a+=swp[k]; c2+=swd[k]; }
    wsums[0]=a; wsums[1]=c2;
  }
  // gather + split into fragment-order LDS
  {
    int m = tid >> 1, hf = tid & 1;      // pair, half (0: x_i dims 0-63, 1: x_j dims 64-127)
    int fl = sidx[m];
    int rc = hf ? (fl & 255) : (fl >> 8);
    const float* src = x + ((size_t)b*L_SEQ + rc)*D_IN;
    int kt = m >> 4, l16 = m & 15;
    #pragma unroll
    for (int g=0; g<8; ++g){
      int d0 = hf*64 + g*8;
      int c = d0 >> 5, q = (d0 >> 3) & 3;
      float v[8];
      *(float4*)&v[0] = *(const float4*)(src + (d0 & 63));
      *(float4*)&v[4] = *(const float4*)(src + (d0 & 63) + 4);
      u32 hp[4], lp[4];
      cvt8(v, hp, lp);
      *(uint4*)&AFh[kt][c][l16 + 16*q][0] = make_uint4(hp[0],hp[1],hp[2],hp[3]);
      *(uint4*)&AFl[kt][c][l16 + 16*q][0] = make_uint4(lp[0],lp[1],lp[2],lp[3]);
    }
  }
  __syncthreads();

  int w = tid >> 6, lane = tid & 63;
  int lm = lane & 15, quad = lane >> 4;

  #pragma unroll
  for (int hi4=0; hi4<4; ++hi4){
    int ht = w + 4*hi4;
    int h  = ht*16 + lm;
    bf16x8 BXh[4], BXl[4], BPh[2], BPl[2];
    #pragma unroll
    for (int c=0;c<4;++c){
      BXh[c] = *(const bf16x8*)(xiH + h*128 + c*32 + quad*8);
      BXl[c] = *(const bf16x8*)(xiL + h*128 + c*32 + quad*8);
    }
    #pragma unroll
    for (int c=0;c<2;++c){
      BPh[c] = *(const bf16x8*)(phiH + h*64 + c*32 + quad*8);
      BPl[c] = *(const bf16x8*)(phiL + h*64 + c*32 + quad*8);
    }
    float bxi = xi_b1[h], bph = phi_b1[h];
    float gp = 0.f, gs = 0.f;
    for (int kt=0; kt<8; ++kt){
      bf16x8 Ah_[4], Al_[4];
      #pragma unroll
      for (int c=0;c<4;++c){
        Ah_[c] = *(const bf16x8*)&AFh[kt][c][lane][0];
        Al_[c] = *(const bf16x8*)&AFl[kt][c][lane][0];
      }
      f32x4 cx = {0.f,0.f,0.f,0.f}, cp = {0.f,0.f,0.f,0.f};
      #pragma unroll
      for (int c=0;c<4;++c){
        cx = __builtin_amdgcn_mfma_f32_16x16x32_bf16(Ah_[c], BXh[c], cx, 0,0,0);
        cx = __builtin_amdgcn_mfma_f32_16x16x32_bf16(Al_[c], BXh[c], cx, 0,0,0);
        cx = __builtin_amdgcn_mfma_f32_16x16x32_bf16(Ah_[c], BXl[c], cx, 0,0,0);
      }
      #pragma unroll
      for (int c=0;c<2;++c){
        cp = __builtin_amdgcn_mfma_f32_16x16x32_bf16(Ah_[c], BPh[c], cp, 0,0,0);
        cp = __builtin_amdgcn_mfma_f32_16x16x32_bf16(Al_[c], BPh[c], cp, 0,0,0);
        cp = __builtin_amdgcn_mfma_f32_16x16x32_bf16(Ah_[c], BPl[c], cp, 0,0,0);
      }
      #pragma unroll
      for (int r=0;r<4;++r){
        int kk = kt*16 + quad*4 + r;
        gp = fmaf(swp[kk], fmaxf(cx[r] + bxi, 0.f), gp);
        gs = fmaf(swd[kk], fmaxf(cp[r] + bph, 0.f), gs);
      }
    }
    gp += __shfl_xor(gp, 16); gp += __shfl_xor(gp, 32);
    gs += __shfl_xor(gs, 16); gs += __shfl_xor(gs, 32);
    if (quad == 0){ gpL[h] = gp; gsL[h] = gs; }
  }
  __syncthreads();

  int h = tid;
  {
    float wsp = wsums[0], wss = wsums[1];
    float po = wsp*xi_b2[h] + wss*phi_b2[h];
    for (int d=0; d<256; ++d){
      po = fmaf(gpL[d], xi_w2[d*HIDN + h], po);
      po = fmaf(gsL[d], phi_w2[d*HIDN + h], po);
    }
    pooled[h] = po;
  }
  __syncthreads();
  {
    float a = rho_b1[h];
    for (int d=0; d<256; ++d) a = fmaf(pooled[d], rho_w1[d*HIDN + h], a);
    t1[h] = fmaxf(a, 0.f);
  }
  __syncthreads();
  if (h < 128){
    float o = rho_b2[h];
    for (int d=0; d<256; ++d) o = fmaf(t1[d], rho_w2[d*128 + h], o);
    out[(size_t)b*128 + h] = o;
  }
}

// ---------- host ----------
extern "C" void kernel_launch(void* const* d_in, const int* in_sizes, int n_in,
                              void* d_out, int out_size, void* d_ws, size_t ws_size,
                              hipStream_t stream)
{
  (void)in_sizes; (void)n_in; (void)out_size; (void)ws_size;
  const float* x      = (const float*)d_in[0];
  const float* Wq     = (const float*)d_in[1];
  const float* bq     = (const float*)d_in[2];
  const float* Wk     = (const float*)d_in[3];
  const float* bk     = (const float*)d_in[4];
  const float* phi_w1 = (const float*)d_in[5];
  const float* phi_b1 = (const float*)d_in[6];
  const float* phi_w2 = (const float*)d_in[7];
  const float* phi_b2 = (const float*)d_in[8];
  const float* xi_w1  = (const float*)d_in[9];
  const float* xi_b1  = (const float*)d_in[10];
  const float* xi_w2  = (const float*)d_in[11];
  const float* xi_b2  = (const float*)d_in[12];
  const float* rho_w1 = (const float*)d_in[13];
  const float* rho_b1 = (const float*)d_in[14];
  const float* rho_w2 = (const float*)d_in[15];
  const float* rho_b2 = (const float*)d_in[16];
  float* out = (float*)d_out;

  float* M      = (float*)d_ws;                               // 4096
  float* uvc    = M + 4096;                                   // 256
  u32*   cand_k = (u32*)(uvc + 256);                          // 512*32*160
  int*   cand_i = (int*)(cand_k + (size_t)B_TOT*NWT*CAP);     // 512*32*160
  int*   cand_n = cand_i + (size_t)B_TOT*NWT*CAP;             // 512*32
  int*   selidx = cand_n + (size_t)B_TOT*NWT;                 // 512*128
  float* selw   = (float*)(selidx + (size_t)B_TOT*TOPK);      // 512*128
  u16*   xiH    = (u16*)(selw + (size_t)B_TOT*TOPK);          // 256*128
  u16*   xiL    = xiH + 256*128;
  u16*   phiH   = xiL + 256*128;                              // 256*64
  u16*   phiL   = phiH + 256*64;

  k_prep <<<dim3(64),          dim3(256), 0, stream>>>(Wq, bq, Wk, bk, M, uvc);
  k_split<<<dim3(192),         dim3(256), 0, stream>>>(xi_w1, phi_w1, xiH, xiL, phiH, phiL);
  k_score<<<dim3(2, 4, B_TOT), dim3(256), 0, stream>>>(x, M, uvc, cand_k, cand_i, cand_n);
  k_merge<<<dim3(B_TOT),       dim3(256), 0, stream>>>(cand_k, cand_i, cand_n, selidx, selw);
  k_mlp  <<<dim3(B_TOT),       dim3(256), 0, stream>>>(x, selidx, selw,
            xiH, xiL, phiH, phiL,
            phi_b1, phi_w2, phi_b2,
            xi_b1, xi_w2, xi_b2,
            rho_w1, rho_b1, rho_w2, rho_b2, out);
}

// Round 5
// 310.443 us; speedup vs baseline: 2.3084x; 1.1848x over previous
//
#include <hip/hip_runtime.h>

typedef unsigned short u16;
typedef unsigned int   u32;
typedef unsigned char  u8;
typedef unsigned long long u64;

#define B_TOT 512
#define L_SEQ 256
#define D_IN  64
#define HIDN  256
#define TOPK  128
#define CAP   160              // candidate cap per wave-tile
#define NWT   32               // wave-tiles per batch: 4 rb x 2 cb x 4 waves

typedef float  f32x4  __attribute__((ext_vector_type(4)));
typedef __bf16 bf16x8 __attribute__((ext_vector_type(8)));

// ---------- helpers ----------
__device__ __forceinline__ u16 f2bf(float f){
  u32 u = __float_as_uint(f);
  u32 r = u + 0x7fffu + ((u>>16)&1u);   // RNE
  return (u16)(r>>16);
}
__device__ __forceinline__ u32 sortKey(float f){
  u32 b = __float_as_uint(f);
  return (b & 0x80000000u) ? ~b : (b | 0x80000000u);
}
__device__ __forceinline__ float unKey(u32 u){
  u32 b = (u & 0x80000000u) ? (u & 0x7fffffffu) : ~u;
  return __uint_as_float(b);
}
__device__ __forceinline__ void cvt8(const float* v, u32* hp, u32* lp){
  #pragma unroll
  for (int i=0;i<4;++i){
    float v0 = v[2*i], v1 = v[2*i+1];
    u16 h0 = f2bf(v0); float h0f = __uint_as_float(((u32)h0)<<16); u16 l0 = f2bf(v0 - h0f);
    u16 h1 = f2bf(v1); float h1f = __uint_as_float(((u32)h1)<<16); u16 l1 = f2bf(v1 - h1f);
    hp[i] = (u32)h0 | ((u32)h1<<16);
    lp[i] = (u32)l0 | ((u32)l1<<16);
  }
}

// ---------- K0: Mt = (Wq Wk^T)^T split bf16, u = Wq bk, v = Wk bq, c = bq.bk ----------
__global__ __launch_bounds__(256) void k_prep(
    const float* __restrict__ Wq, const float* __restrict__ bq,
    const float* __restrict__ Wk, const float* __restrict__ bk,
    u16* __restrict__ MtH, u16* __restrict__ MtL, float* __restrict__ uvc)
{
  __shared__ float wq[HIDN];
  __shared__ float part[256];
  int a = blockIdx.x, tid = threadIdx.x;
  wq[tid] = Wq[a*HIDN + tid];
  __syncthreads();
  int bcol = tid & 63, q = tid >> 6;
  float s = 0.f;
  for (int h = q*64; h < q*64 + 64; ++h)
    s = fmaf(wq[h], Wk[bcol*HIDN + h], s);
  part[tid] = s;
  __syncthreads();
  if (tid < 64){
    float mv = part[tid] + part[64+tid] + part[128+tid] + part[192+tid];
    u16 hh = f2bf(mv); float hf = __uint_as_float(((u32)hh)<<16);
    u16 ll = f2bf(mv - hf);
    MtH[tid*64 + a] = hh;          // Mt[c][a] = M[a][c]
    MtL[tid*64 + a] = ll;
  }
  if (tid == 0){
    float su = 0.f;
    for (int h=0; h<HIDN; ++h) su = fmaf(wq[h], bk[h], su);
    uvc[a] = su;
  }
  if (tid == 1){
    float sv = 0.f;
    for (int h=0; h<HIDN; ++h) sv = fmaf(Wk[a*HIDN + h], bq[h], sv);
    uvc[64 + a] = sv;
  }
  if (a == 0 && tid == 2){
    float c = 0.f;
    for (int h=0; h<HIDN; ++h) c = fmaf(bq[h], bk[h], c);
    uvc[128] = c;
  }
}

// ---------- K0b: split+transpose MLP layer-1 weights into [h][d] hi/lo bf16 ----------
__global__ __launch_bounds__(256) void k_split(
    const float* __restrict__ xi_w1, const float* __restrict__ phi_w1,
    u16* __restrict__ xiH, u16* __restrict__ xiL,
    u16* __restrict__ phiH, u16* __restrict__ phiL)
{
  int t = blockIdx.x*256 + threadIdx.x;
  if (t < 256*128){
    int h = t >> 7, d = t & 127;
    float v = xi_w1[d*HIDN + h];
    u16 hh = f2bf(v); float hf = __uint_as_float(((u32)hh)<<16);
    u16 ll = f2bf(v - hf);
    xiH[h*128 + d] = hh; xiL[h*128 + d] = ll;
  } else {
    int t2 = t - 256*128;
    int h = t2 >> 6, d = t2 & 63;
    float v = phi_w1[d*HIDN + h];
    u16 hh = f2bf(v); float hf = __uint_as_float(((u32)hh)<<16);
    u16 ll = f2bf(v - hf);
    phiH[h*64 + d] = hh; phiL[h*64 + d] = ll;
  }
}

// ---------- K0c: split x -> xh/xl; s,t,pad; y = x M via MFMA -> yh/yl ----------
// grid 2048 (64 rows each), block 256
__global__ __launch_bounds__(256) void k_pre(
    const float* __restrict__ x, const u16* __restrict__ MtH, const u16* __restrict__ MtL,
    const float* __restrict__ uvc,
    u16* __restrict__ xh, u16* __restrict__ xl,
    u16* __restrict__ yh, u16* __restrict__ yl,
    float* __restrict__ st, u8* __restrict__ padm)
{
  __shared__ __align__(16) u16 sh[64][72];
  __shared__ __align__(16) u16 sl[64][72];
  __shared__ float sUV[132];
  int tid = threadIdx.x;
  int g0 = blockIdx.x * 64;         // 64 rows, never crosses a batch boundary
  int b  = g0 >> 8, l0 = g0 & 255;
  int r = tid >> 2, q = tid & 3;

  if (tid < 129) sUV[tid] = uvc[tid];

  float v[16];
  {
    const float* xr = x + (size_t)(g0 + r)*D_IN + q*16;
    #pragma unroll
    for (int i=0;i<4;++i) *(float4*)&v[i*4] = *(const float4*)(xr + i*4);
  }
  // split x -> global + LDS (A-operand layout rows)
  {
    u32 hpA[4],lpA[4],hpB[4],lpB[4];
    cvt8(&v[0], hpA, lpA); cvt8(&v[8], hpB, lpB);
    size_t xo = (size_t)(g0 + r)*D_IN + q*16;
    *(uint4*)(xh + xo)     = make_uint4(hpA[0],hpA[1],hpA[2],hpA[3]);
    *(uint4*)(xh + xo + 8) = make_uint4(hpB[0],hpB[1],hpB[2],hpB[3]);
    *(uint4*)(xl + xo)     = make_uint4(lpA[0],lpA[1],lpA[2],lpA[3]);
    *(uint4*)(xl + xo + 8) = make_uint4(lpB[0],lpB[1],lpB[2],lpB[3]);
    *(uint4*)&sh[r][q*16]   = make_uint4(hpA[0],hpA[1],hpA[2],hpA[3]);
    *(uint4*)&sh[r][q*16+8] = make_uint4(hpB[0],hpB[1],hpB[2],hpB[3]);
    *(uint4*)&sl[r][q*16]   = make_uint4(lpA[0],lpA[1],lpA[2],lpA[3]);
    *(uint4*)&sl[r][q*16+8] = make_uint4(lpB[0],lpB[1],lpB[2],lpB[3]);
  }
  __syncthreads();

  // s_i, t_j, pad (partials over own 16 dims, combine across q via shuffle)
  {
    float su=0.f, tv=0.f, pa=0.f;
    #pragma unroll
    for (int d=0; d<16; ++d){
      float xa = v[d];
      su = fmaf(xa, sUV[q*16+d], su);
      tv = fmaf(xa, sUV[64+q*16+d], tv);
      pa += fabsf(xa);
    }
    su += __shfl_xor(su,1); su += __shfl_xor(su,2);
    tv += __shfl_xor(tv,1); tv += __shfl_xor(tv,2);
    pa += __shfl_xor(pa,1); pa += __shfl_xor(pa,2);
    if (q == 0){
      st[(size_t)b*L_SEQ + l0 + r]           = su + sUV[128];
      st[(size_t)(B_TOT+b)*L_SEQ + l0 + r]   = tv;
      padm[(size_t)b*L_SEQ + l0 + r] = (pa != 0.f) ? 1 : 0;
    }
  }

  // y = x M via split-bf16 MFMA (3-product)
  int w = tid >> 6, lane = tid & 63, lm = lane & 15, quad = lane >> 4;
  bf16x8 Ah0 = *(const bf16x8*)&sh[w*16+lm][quad*8];
  bf16x8 Ah1 = *(const bf16x8*)&sh[w*16+lm][32 + quad*8];
  bf16x8 Al0 = *(const bf16x8*)&sl[w*16+lm][quad*8];
  bf16x8 Al1 = *(const bf16x8*)&sl[w*16+lm][32 + quad*8];
  #pragma unroll
  for (int ct=0; ct<4; ++ct){
    const u16* mth = MtH + (ct*16+lm)*64 + quad*8;
    const u16* mtl = MtL + (ct*16+lm)*64 + quad*8;
    bf16x8 Bh0 = *(const bf16x8*)(mth);
    bf16x8 Bh1 = *(const bf16x8*)(mth + 32);
    bf16x8 Bl0 = *(const bf16x8*)(mtl);
    bf16x8 Bl1 = *(const bf16x8*)(mtl + 32);
    f32x4 acc = {0.f,0.f,0.f,0.f};
    acc = __builtin_amdgcn_mfma_f32_16x16x32_bf16(Ah0, Bh0, acc, 0,0,0);
    acc = __builtin_amdgcn_mfma_f32_16x16x32_bf16(Ah1, Bh1, acc, 0,0,0);
    acc = __builtin_amdgcn_mfma_f32_16x16x32_bf16(Al0, Bh0, acc, 0,0,0);
    acc = __builtin_amdgcn_mfma_f32_16x16x32_bf16(Al1, Bh1, acc, 0,0,0);
    acc = __builtin_amdgcn_mfma_f32_16x16x32_bf16(Ah0, Bl0, acc, 0,0,0);
    acc = __builtin_amdgcn_mfma_f32_16x16x32_bf16(Ah1, Bl1, acc, 0,0,0);
    #pragma unroll
    for (int rg=0; rg<4; ++rg){
      float vy = acc[rg];
      u16 hh = f2bf(vy); float hf = __uint_as_float(((u32)hh)<<16);
      u16 ll = f2bf(vy - hf);
      size_t row = (size_t)g0 + w*16 + quad*4 + rg;
      yh[row*D_IN + ct*16 + lm] = hh;
      yl[row*D_IN + ct*16 + lm] = ll;
    }
  }
}

// ---------- K1: scores = (y x^T + s_i + t_j)/16 via MFMA, per-wave top-k superset ----------
// grid dim3(2 cb, 4 rb, B): block tile 64 rows x 128 cols; block 256; NO LDS, NO barriers
__global__ __launch_bounds__(256) void k_score(
    const u16* __restrict__ xh, const u16* __restrict__ xl,
    const u16* __restrict__ yh, const u16* __restrict__ yl,
    const float* __restrict__ st, const u8* __restrict__ padm,
    u32* __restrict__ cand_k, int* __restrict__ cand_i, int* __restrict__ cand_n)
{
  int tid = threadIdx.x;
  int cb = blockIdx.x, rb = blockIdx.y, b = blockIdx.z;
  int r0 = rb*64, j0 = cb*128;
  int w = tid >> 6, lane = tid & 63, lm = lane & 15, quad = lane >> 4;

  // A-frags: y rows
  size_t rowA = ((size_t)b*L_SEQ + r0 + w*16 + lm)*D_IN;
  bf16x8 A_h0 = *(const bf16x8*)(yh + rowA + quad*8);
  bf16x8 A_h1 = *(const bf16x8*)(yh + rowA + 32 + quad*8);
  bf16x8 A_l0 = *(const bf16x8*)(yl + rowA + quad*8);
  bf16x8 A_l1 = *(const bf16x8*)(yl + rowA + 32 + quad*8);

  // rank-1 terms + pad
  float sr4[4]; u32 prb[4];
  #pragma unroll
  for (int r=0;r<4;++r){
    int l = r0 + w*16 + quad*4 + r;
    sr4[r] = st[(size_t)b*L_SEQ + l];
    prb[r] = padm[(size_t)b*L_SEQ + l];
  }
  float tc[8]; u32 pcb[8];
  #pragma unroll
  for (int ct=0;ct<8;++ct){
    int j = j0 + ct*16 + lm;
    tc[ct]  = st[(size_t)(B_TOT + b)*L_SEQ + j];
    pcb[ct] = padm[(size_t)b*L_SEQ + j];
  }

  const float NINF = __uint_as_float(0xff800000u);
  float av[32];
  #pragma unroll
  for (int ct=0; ct<8; ++ct){
    size_t rowB = ((size_t)b*L_SEQ + j0 + ct*16 + lm)*D_IN;
    bf16x8 B_h0 = *(const bf16x8*)(xh + rowB + quad*8);
    bf16x8 B_h1 = *(const bf16x8*)(xh + rowB + 32 + quad*8);
    bf16x8 B_l0 = *(const bf16x8*)(xl + rowB + quad*8);
    bf16x8 B_l1 = *(const bf16x8*)(xl + rowB + 32 + quad*8);
    f32x4 acc = {0.f,0.f,0.f,0.f};
    acc = __builtin_amdgcn_mfma_f32_16x16x32_bf16(A_h0, B_h0, acc, 0,0,0);
    acc = __builtin_amdgcn_mfma_f32_16x16x32_bf16(A_h1, B_h1, acc, 0,0,0);
    acc = __builtin_amdgcn_mfma_f32_16x16x32_bf16(A_l0, B_h0, acc, 0,0,0);
    acc = __builtin_amdgcn_mfma_f32_16x16x32_bf16(A_l1, B_h1, acc, 0,0,0);
    acc = __builtin_amdgcn_mfma_f32_16x16x32_bf16(A_h0, B_l0, acc, 0,0,0);
    acc = __builtin_amdgcn_mfma_f32_16x16x32_bf16(A_h1, B_l1, acc, 0,0,0);
    bool pc = pcb[ct] != 0;
    #pragma unroll
    for (int r=0;r<4;++r){
      bool ok = pc && (prb[r] != 0);
      float vv = ok ? (acc[r] + sr4[r] + tc[ct])*0.0625f : NINF;
      av[ct*4 + r] = __uint_as_float(sortKey(vv));
    }
  }

  // per-wave 16-bit-prefix threshold via ballot counting, early-exit in [TOPK, CAP]
  u32 T = 0;
  for (int bit=15; bit>=0; --bit){
    u32 cnd = T | (1u<<bit);
    u32 th2 = cnd << 16;
    int c = 0;
    #pragma unroll
    for (int i=0;i<32;++i)
      c += (int)__popcll(__ballot(__float_as_uint(av[i]) >= th2));
    if (c >= TOPK){
      T = cnd;
      if (c <= CAP) break;
    }
  }
  u32 thr = T << 16;

  // emit all keys >= thr (superset of wave-tile top-128)
  int myc = 0;
  #pragma unroll
  for (int i=0;i<32;++i) myc += (__float_as_uint(av[i]) >= thr) ? 1 : 0;
  int pre = myc;
  #pragma unroll
  for (int off=1; off<64; off<<=1){
    int n = __shfl_up(pre, off);
    if (lane >= off) pre += n;
  }
  int total = __shfl(pre, 63);
  int pos = pre - myc;
  int wt = (rb*2 + cb)*4 + w;
  size_t base = ((size_t)b*NWT + wt)*CAP;
  if (lane == 0) cand_n[b*NWT + wt] = (total < CAP) ? total : CAP;
  #pragma unroll
  for (int i=0;i<32;++i){
    u32 u = __float_as_uint(av[i]);
    if (u >= thr && pos < CAP){
      int r = i & 3, ct = i >> 2;
      int row = r0 + w*16 + quad*4 + r;
      int col = j0 + ct*16 + lm;
      cand_k[base + pos] = u;
      cand_i[base + pos] = row*L_SEQ + col;
      ++pos;
    }
  }
}

// ---------- K2: exact merge of <=32x160 candidates -> top-128 + softmax ----------
__global__ __launch_bounds__(256) void k_merge(
    const u32* __restrict__ cand_k, const int* __restrict__ cand_i, const int* __restrict__ cand_n,
    int* __restrict__ selidx, float* __restrict__ selw)
{
  __shared__ int red32[34];
  __shared__ int cnts[NWT];
  __shared__ int cm, eqc;
  __shared__ int eqi[256];
  __shared__ float sv[TOPK]; __shared__ int si[TOPK];
  __shared__ float fred[8];
  int b = blockIdx.x, tid = threadIdx.x;
  const int NS = NWT*CAP/256;   // 20
  if (tid < NWT) cnts[tid] = cand_n[b*NWT + tid];
  if (tid < 34) red32[tid] = 0;
  if (tid == 0){ cm = 0; eqc = 0; }
  __syncthreads();

  u32 key[NS]; int idx[NS];
  size_t bb = (size_t)b*NWT*CAP;
  #pragma unroll
  for (int s=0;s<NS;++s){
    int e = tid + 256*s;
    int slot = e / CAP, p = e - slot*CAP;
    bool ok = p < cnts[slot];
    key[s] = ok ? cand_k[bb + e] : 0u;
    idx[s] = ok ? cand_i[bb + e] : 0x7fffffff;
  }

  u32 T = 0;
  for (int bit=31; bit>=0; --bit){
    u32 c2 = T | (1u<<bit);
    int c = 0;
    #pragma unroll
    for (int s=0;s<NS;++s) c += (key[s] >= c2) ? 1 : 0;
    #pragma unroll
    for (int off=1; off<64; off<<=1) c += __shfl_xor(c, off);
    if ((tid&63)==0) atomicAdd(&red32[31-bit], c);
    __syncthreads();
    if (red32[31-bit] >= TOPK) T = c2;
  }
  {
    int c = 0;
    #pragma unroll
    for (int s=0;s<NS;++s) c += (key[s] > T) ? 1 : 0;
    #pragma unroll
    for (int off=1; off<64; off<<=1) c += __shfl_xor(c, off);
    if ((tid&63)==0) atomicAdd(&red32[33], c);
  }
  __syncthreads();
  int m = red32[33];

  #pragma unroll
  for (int s=0;s<NS;++s){
    if (key[s] > T){
      int p = atomicAdd(&cm, 1);
      sv[p] = unKey(key[s]); si[p] = idx[s];
    } else if (key[s] == T && key[s] != 0u){
      int q = atomicAdd(&eqc, 1);
      if (q < 256) eqi[q] = idx[s];
    }
  }
  __syncthreads();
  if (tid == 0){
    int need = TOPK - m;
    int n = eqc < 256 ? eqc : 256;
    float tv = unKey(T);
    for (int s2=0; s2<need; ++s2){
      int bi = s2;
      for (int j=s2+1;j<n;++j) if (eqi[j] < eqi[bi]) bi = j;
      int t2 = eqi[s2]; eqi[s2] = eqi[bi]; eqi[bi] = t2;
      sv[m+s2] = tv; si[m+s2] = eqi[s2];
    }
  }
  __syncthreads();

  float v = (tid < TOPK) ? sv[tid] : -3.4e38f;
  float mx = v;
  #pragma unroll
  for (int off=1; off<64; off<<=1) mx = fmaxf(mx, __shfl_xor(mx, off));
  if ((tid&63)==0) fred[tid>>6] = mx;
  __syncthreads();
  mx = fmaxf(fred[0], fred[1]);
  float e = (tid < TOPK) ? expf(v - mx) : 0.f;
  float s = e;
  #pragma unroll
  for (int off=1; off<64; off<<=1) s += __shfl_xor(s, off);
  if ((tid&63)==0) fred[4 + (tid>>6)] = s;
  __syncthreads();
  s = fred[4] + fred[5];
  if (tid < TOPK){
    selw[(size_t)b*TOPK + tid]   = e / s;
    selidx[(size_t)b*TOPK + tid] = si[tid];
  }
}

// ---------- K3: gather + split-bf16 MFMA MLP1 + weighted pooling (layer2 fused) + rho ----------
__global__ __launch_bounds__(256) void k_mlp(
    const float* __restrict__ x, const int* __restrict__ selidx, const float* __restrict__ selw,
    const u16* __restrict__ xiH, const u16* __restrict__ xiL,
    const u16* __restrict__ phiH, const u16* __restrict__ phiL,
    const float* __restrict__ phi_b1, const float* __restrict__ phi_w2, const float* __restrict__ phi_b2,
    const float* __restrict__ xi_b1,  const float* __restrict__ xi_w2,  const float* __restrict__ xi_b2,
    const float* __restrict__ rho_w1, const float* __restrict__ rho_b1,
    const float* __restrict__ rho_w2, const float* __restrict__ rho_b2,
    float* __restrict__ out)
{
  __shared__ __align__(16) u16 AFh[8][4][64][8];
  __shared__ __align__(16) u16 AFl[8][4][64][8];
  __shared__ int   sidx[TOPK];
  __shared__ float swp[TOPK], swd[TOPK];
  __shared__ float gpL[256], gsL[256];
  __shared__ float pooled[256], t1[256];
  __shared__ float wsums[2];
  int b = blockIdx.x, tid = threadIdx.x;

  if (tid < TOPK){
    int fl = selidx[(size_t)b*TOPK + tid];
    sidx[tid] = fl;
    float wv = selw[(size_t)b*TOPK + tid];
    bool dg = ((fl>>8) == (fl&255));
    swp[tid] = dg ? 0.f : wv;
    swd[tid] = dg ? wv  : 0.f;
  }
  __syncthreads();
  if (tid == 0){
    float a=0.f, c2=0.f;
    for (int k=0;k<TOPK;++k){ a+=swp[k]; c2+=swd[k]; }
    wsums[0]=a; wsums[1]=c2;
  }
  {
    int m = tid >> 1, hf = tid & 1;
    int fl = sidx[m];
    int rc = hf ? (fl & 255) : (fl >> 8);
    const float* src = x + ((size_t)b*L_SEQ + rc)*D_IN;
    int kt = m >> 4, l16 = m & 15;
    #pragma unroll
    for (int g=0; g<8; ++g){
      int d0 = hf*64 + g*8;
      int c = d0 >> 5, q = (d0 >> 3) & 3;
      float v[8];
      *(float4*)&v[0] = *(const float4*)(src + (d0 & 63));
      *(float4*)&v[4] = *(const float4*)(src + (d0 & 63) + 4);
      u32 hp[4], lp[4];
      cvt8(v, hp, lp);
      *(uint4*)&AFh[kt][c][l16 + 16*q][0] = make_uint4(hp[0],hp[1],hp[2],hp[3]);
      *(uint4*)&AFl[kt][c][l16 + 16*q][0] = make_uint4(lp[0],lp[1],lp[2],lp[3]);
    }
  }
  __syncthreads();

  int w = tid >> 6, lane = tid & 63;
  int lm = lane & 15, quad = lane >> 4;

  #pragma unroll
  for (int hi4=0; hi4<4; ++hi4){
    int ht = w + 4*hi4;
    int h  = ht*16 + lm;
    bf16x8 BXh[4], BXl[4], BPh[2], BPl[2];
    #pragma unroll
    for (int c=0;c<4;++c){
      BXh[c] = *(const bf16x8*)(xiH + h*128 + c*32 + quad*8);
      BXl[c] = *(const bf16x8*)(xiL + h*128 + c*32 + quad*8);
    }
    #pragma unroll
    for (int c=0;c<2;++c){
      BPh[c] = *(const bf16x8*)(phiH + h*64 + c*32 + quad*8);
      BPl[c] = *(const bf16x8*)(phiL + h*64 + c*32 + quad*8);
    }
    float bxi = xi_b1[h], bph = phi_b1[h];
    float gp = 0.f, gs = 0.f;
    for (int kt=0; kt<8; ++kt){
      bf16x8 Ah_[4], Al_[4];
      #pragma unroll
      for (int c=0;c<4;++c){
        Ah_[c] = *(const bf16x8*)&AFh[kt][c][lane][0];
        Al_[c] = *(const bf16x8*)&AFl[kt][c][lane][0];
      }
      f32x4 cx = {0.f,0.f,0.f,0.f}, cp = {0.f,0.f,0.f,0.f};
      #pragma unroll
      for (int c=0;c<4;++c){
        cx = __builtin_amdgcn_mfma_f32_16x16x32_bf16(Ah_[c], BXh[c], cx, 0,0,0);
        cx = __builtin_amdgcn_mfma_f32_16x16x32_bf16(Al_[c], BXh[c], cx, 0,0,0);
        cx = __builtin_amdgcn_mfma_f32_16x16x32_bf16(Ah_[c], BXl[c], cx, 0,0,0);
      }
      #pragma unroll
      for (int c=0;c<2;++c){
        cp = __builtin_amdgcn_mfma_f32_16x16x32_bf16(Ah_[c], BPh[c], cp, 0,0,0);
        cp = __builtin_amdgcn_mfma_f32_16x16x32_bf16(Al_[c], BPh[c], cp, 0,0,0);
        cp = __builtin_amdgcn_mfma_f32_16x16x32_bf16(Ah_[c], BPl[c], cp, 0,0,0);
      }
      #pragma unroll
      for (int r=0;r<4;++r){
        int kk = kt*16 + quad*4 + r;
        gp = fmaf(swp[kk], fmaxf(cx[r] + bxi, 0.f), gp);
        gs = fmaf(swd[kk], fmaxf(cp[r] + bph, 0.f), gs);
      }
    }
    gp += __shfl_xor(gp, 16); gp += __shfl_xor(gp, 32);
    gs += __shfl_xor(gs, 16); gs += __shfl_xor(gs, 32);
    if (quad == 0){ gpL[h] = gp; gsL[h] = gs; }
  }
  __syncthreads();

  int h = tid;
  {
    float wsp = wsums[0], wss = wsums[1];
    float po = wsp*xi_b2[h] + wss*phi_b2[h];
    for (int d=0; d<256; ++d){
      po = fmaf(gpL[d], xi_w2[d*HIDN + h], po);
      po = fmaf(gsL[d], phi_w2[d*HIDN + h], po);
    }
    pooled[h] = po;
  }
  __syncthreads();
  {
    float a = rho_b1[h];
    for (int d=0; d<256; ++d) a = fmaf(pooled[d], rho_w1[d*HIDN + h], a);
    t1[h] = fmaxf(a, 0.f);
  }
  __syncthreads();
  if (h < 128){
    float o = rho_b2[h];
    for (int d=0; d<256; ++d) o = fmaf(t1[d], rho_w2[d*128 + h], o);
    out[(size_t)b*128 + h] = o;
  }
}

// ---------- host ----------
extern "C" void kernel_launch(void* const* d_in, const int* in_sizes, int n_in,
                              void* d_out, int out_size, void* d_ws, size_t ws_size,
                              hipStream_t stream)
{
  (void)in_sizes; (void)n_in; (void)out_size; (void)ws_size;
  const float* x      = (const float*)d_in[0];
  const float* Wq     = (const float*)d_in[1];
  const float* bq     = (const float*)d_in[2];
  const float* Wk     = (const float*)d_in[3];
  const float* bk     = (const float*)d_in[4];
  const float* phi_w1 = (const float*)d_in[5];
  const float* phi_b1 = (const float*)d_in[6];
  const float* phi_w2 = (const float*)d_in[7];
  const float* phi_b2 = (const float*)d_in[8];
  const float* xi_w1  = (const float*)d_in[9];
  const float* xi_b1  = (const float*)d_in[10];
  const float* xi_w2  = (const float*)d_in[11];
  const float* xi_b2  = (const float*)d_in[12];
  const float* rho_w1 = (const float*)d_in[13];
  const float* rho_b1 = (const float*)d_in[14];
  const float* rho_w2 = (const float*)d_in[15];
  const float* rho_b2 = (const float*)d_in[16];
  float* out = (float*)d_out;

  const size_t NX = (size_t)B_TOT*L_SEQ*D_IN;      // 8,388,608
  float* uvc    = (float*)d_ws;                    // 256
  float* st     = uvc + 256;                       // 2*512*256
  float* selw   = st + (size_t)2*B_TOT*L_SEQ;      // 512*128
  u32*   cand_k = (u32*)(selw + (size_t)B_TOT*TOPK);
  int*   cand_i = (int*)(cand_k + (size_t)B_TOT*NWT*CAP);
  int*   cand_n = cand_i + (size_t)B_TOT*NWT*CAP;
  int*   selidx = cand_n + (size_t)B_TOT*NWT;
  u16*   MtH    = (u16*)(selidx + (size_t)B_TOT*TOPK);
  u16*   MtL    = MtH + 64*64;
  u16*   xiH    = MtL + 64*64;
  u16*   xiL    = xiH + 256*128;
  u16*   phiH   = xiL + 256*128;
  u16*   phiL   = phiH + 256*64;
  u16*   xh     = phiL + 256*64;
  u16*   xl     = xh + NX;
  u16*   yh     = xl + NX;
  u16*   yl     = yh + NX;
  u8*    padm   = (u8*)(yl + NX);                  // 512*256

  k_prep <<<dim3(64),          dim3(256), 0, stream>>>(Wq, bq, Wk, bk, MtH, MtL, uvc);
  k_split<<<dim3(192),         dim3(256), 0, stream>>>(xi_w1, phi_w1, xiH, xiL, phiH, phiL);
  k_pre  <<<dim3(2048),        dim3(256), 0, stream>>>(x, MtH, MtL, uvc, xh, xl, yh, yl, st, padm);
  k_score<<<dim3(2, 4, B_TOT), dim3(256), 0, stream>>>(xh, xl, yh, yl, st, padm, cand_k, cand_i, cand_n);
  k_merge<<<dim3(B_TOT),       dim3(256), 0, stream>>>(cand_k, cand_i, cand_n, selidx, selw);
  k_mlp  <<<dim3(B_TOT),       dim3(256), 0, stream>>>(x, selidx, selw,
            xiH, xiL, phiH, phiL,
            phi_b1, phi_w2, phi_b2,
            xi_b1, xi_w2, xi_b2,
            rho_w1, rho_b1, rho_w2, rho_b2, out);
}